// Round 9
// baseline (359.761 us; speedup 1.0000x reference)
//
#include <hip/hip_runtime.h>
#include <hip/hip_bf16.h>
#include <hip/hip_fp16.h>
#include <math.h>

#define N_TOKENS 16
#define TOK_DIM 64
#define NODE_DIM 64
#define HID 128
#define FC 128
#define NUM_GRAPHS 1024
#define NBUCK_MAX 512
#define CHUNK 8192

typedef _Float16 f16x8 __attribute__((ext_vector_type(8)));
typedef float f32x4 __attribute__((ext_vector_type(4)));

__device__ __forceinline__ __half2 shfl_xor_h2(__half2 v, int mask) {
    int i = *(int*)&v;
    i = __shfl_xor(i, mask);
    return *(__half2*)&i;
}

// ---------------- fused prep: weights (blocks 0..127) + emb fp32->fp16 + deg zero ----------------
__global__ void prep_fused_kernel(const float* __restrict__ Wp, const float* __restrict__ W1,
                                  const float* __restrict__ W2, const float* __restrict__ bp,
                                  const float* __restrict__ emb,
                                  _Float16* __restrict__ Wf16t, _Float16* __restrict__ W2t,
                                  float* __restrict__ bf, __half* __restrict__ emb16, int n4,
                                  int embB, int* __restrict__ deg, int ndeg) {
    int b = blockIdx.x;
    int t = threadIdx.x;
    if (b < 128) {
        int n = b;
        if (t < 64) {
            float acc = 0.f;
#pragma unroll
            for (int d = 0; d < 64; d++) acc += Wp[t * 64 + d] * W1[d * 128 + n];
            Wf16t[(size_t)n * 64 + t] = (_Float16)acc;
        } else if (t < 128) {
            int d = t - 64;  // lane of wave 1
            float v = bp[d] * W1[d * 128 + n];
#pragma unroll
            for (int off = 32; off > 0; off >>= 1) v += __shfl_down(v, off);
            if (d == 0) bf[n] = v;
        }
        if (t < 128) W2t[(size_t)n * 128 + t] = (_Float16)W2[(size_t)t * 128 + n];
    } else if (b < 128 + embB) {
        int i = (b - 128) * 256 + t;
        if (i < n4) {
            float4 v = ((const float4*)emb)[i];
            __half2 h0 = __floats2half2_rn(v.x, v.y);
            __half2 h1 = __floats2half2_rn(v.z, v.w);
            float2 p;
            ((__half2*)&p)[0] = h0;
            ((__half2*)&p)[1] = h1;
            ((float2*)emb16)[i] = p;
        }
    } else {
        int i = (b - 128 - embB) * 256 + t;
        if (i < ndeg) deg[i] = 0;
    }
}

// ---------------- combined: bucket hist + per-node deg atomics (blocks 0..nchunk-1)
//                  + embed/token-mean (rest) ----------------
__global__ void hist_embed_kernel(const int* __restrict__ dst, int* __restrict__ hist2d,
                                  int E, int nbuck, int nchunk, int* __restrict__ deg,
                                  const int* __restrict__ tok,
                                  const __half* __restrict__ emb16,
                                  __half* __restrict__ mean16, int N) {
    int b = blockIdx.x;
    int t = threadIdx.x;
    if (b < nchunk) {
        __shared__ int h[NBUCK_MAX];
        for (int i = t; i < nbuck; i += 512) h[i] = 0;
        __syncthreads();
        int base = b * CHUNK;
        for (int i = t; i < CHUNK; i += 512) {
            int e = base + i;
            if (e < E) {
                int d = dst[e];
                atomicAdd(&h[d >> 8], 1);
                atomicAdd(&deg[d], 1);
            }
        }
        __syncthreads();
        int* row = hist2d + (size_t)b * NBUCK_MAX;
        for (int i = t; i < nbuck; i += 512) row[i] = h[i];
    } else {
        int w = t >> 6, j = t & 63;
        int q = j >> 3, l = j & 7;
        int i = (b - nchunk) * 8 + w;
        if (i >= N) return;
        const float4* e4 = (const float4*)emb16;  // row = 8 float4 (64 halfs)
        int t0 = tok[i * 16 + q];
        int t1 = tok[i * 16 + q + 8];
        float4 v0 = e4[(size_t)t0 * 8 + l];
        float4 v1 = e4[(size_t)t1 * 8 + l];
        const __half2* p0 = (const __half2*)&v0;
        const __half2* p1 = (const __half2*)&v1;
        __half2 a0 = __hadd2(p0[0], p1[0]);
        __half2 a1 = __hadd2(p0[1], p1[1]);
        __half2 a2 = __hadd2(p0[2], p1[2]);
        __half2 a3 = __hadd2(p0[3], p1[3]);
#pragma unroll
        for (int mask = 8; mask <= 32; mask <<= 1) {
            a0 = __hadd2(a0, shfl_xor_h2(a0, mask));
            a1 = __hadd2(a1, shfl_xor_h2(a1, mask));
            a2 = __hadd2(a2, shfl_xor_h2(a2, mask));
            a3 = __hadd2(a3, shfl_xor_h2(a3, mask));
        }
        if (q == 0) {
            __half2 inv = __floats2half2_rn(1.0f / 16.0f, 1.0f / 16.0f);
            float4 packed;
            __half2* pp = (__half2*)&packed;
            pp[0] = __hmul2(a0, inv);
            pp[1] = __hmul2(a1, inv);
            pp[2] = __hmul2(a2, inv);
            pp[3] = __hmul2(a3, inv);
            ((float4*)mean16)[(size_t)i * 8 + l] = packed;
        }
    }
}

// per-bucket exclusive scan over chunks -> chunkbase[chunk][bucket], total[bucket]
// ALSO computes dis[] for this bucket's 256 nodes from deg[] (breaks the cross-bucket
// dependency that forced a separate bucket_count kernel).
// grid = nbuck blocks x 64 threads (one wave each)
__global__ void chunk_scan_kernel(const int* __restrict__ hist2d, int* __restrict__ chunkbase,
                                  int* __restrict__ total, int nchunk,
                                  const int* __restrict__ deg, float* __restrict__ dis, int N) {
    int b = blockIdx.x;
    int lane = threadIdx.x;  // 0..63
    int run = 0;
    for (int c0 = 0; c0 < nchunk; c0 += 64) {
        int c = c0 + lane;
        int v = (c < nchunk) ? hist2d[(size_t)c * NBUCK_MAX + b] : 0;
        int s = v;
#pragma unroll
        for (int off = 1; off < 64; off <<= 1) {
            int u = __shfl_up(s, off);
            if (lane >= off) s += u;
        }
        if (c < nchunk) chunkbase[(size_t)c * NBUCK_MAX + b] = s - v + run;
        run += __shfl(s, 63);
    }
    if (lane == 0) total[b] = run;
    int nb = b * 256;
#pragma unroll
    for (int i = 0; i < 4; i++) {
        int node = nb + lane + i * 64;
        if (node < N) dis[node] = rsqrtf(1.0f + (float)deg[node]);
    }
}

// one-pass scatter; each block re-derives bucket_base from total[] via LDS scan.
// packed val = src | (dst&255)<<17
__global__ void binscatter_kernel(const int* __restrict__ src, const int* __restrict__ dst,
                                  const int* __restrict__ total,
                                  const int* __restrict__ chunkbase,
                                  int* __restrict__ staged, int E, int nbuck) {
    __shared__ int s[512];
    __shared__ int h[NBUCK_MAX];
    int t = threadIdx.x;
    int v = (t < nbuck) ? total[t] : 0;
    s[t] = v;
    __syncthreads();
    for (int off = 1; off < 512; off <<= 1) {
        int add = (t >= off) ? s[t - off] : 0;
        __syncthreads();
        s[t] += add;
        __syncthreads();
    }
    const int* cb = chunkbase + (size_t)blockIdx.x * NBUCK_MAX;
    if (t < nbuck) h[t] = (s[t] - v) + cb[t];
    __syncthreads();
    int base = blockIdx.x * CHUNK;
    for (int i = t; i < CHUNK; i += 512) {
        int e = base + i;
        if (e < E) {
            int d = dst[e], sv = src[e];
            int b = d >> 8;
            int r = atomicAdd(&h[b], 1);
            staged[r] = sv | ((d & 255) << 17);
        }
    }
}

// merged (replaces bucket_count + csr_write): per bucket, 512 threads.
// Re-derives bucket_base from total[] (LDS scan), scans deg -> row_start, then
// scatters staged -> final CSR (src, half2(w,w)) + rowsum. dis[] fully ready (chunk_scan).
__global__ void csr_merged_kernel(const int* __restrict__ staged,
                                  const int* __restrict__ total,
                                  const int* __restrict__ deg,
                                  const float* __restrict__ dis,
                                  int* __restrict__ row_start,
                                  int2* __restrict__ csr, float* __restrict__ rowsum,
                                  int N, int E, int nbuck) {
    __shared__ int s[512];
    __shared__ int sc[256];
    __shared__ int cur[256];
    __shared__ float dl[256];
    __shared__ float wsum[256];
    int b = blockIdx.x;
    int t = threadIdx.x;
    // bucket_base scan over totals (512-wide, inclusive)
    int v = (t < nbuck) ? total[t] : 0;
    s[t] = v;
    __syncthreads();
    for (int off = 1; off < 512; off <<= 1) {
        int add = (t >= off) ? s[t - off] : 0;
        __syncthreads();
        s[t] += add;
        __syncthreads();
    }
    int myTot = total[b];
    int rb0 = s[b] - myTot;   // exclusive base of this bucket
    int rb1 = rb0 + myTot;
    // intra-bucket node scan of deg -> row_start
    int node = b * 256 + t;
    int dv = 0;
    if (t < 256) {
        dv = (node < N) ? deg[node] : 0;
        sc[t] = dv;
    }
    __syncthreads();
    for (int off = 1; off < 256; off <<= 1) {
        int add = (t < 256 && t >= off) ? sc[t - off] : 0;
        __syncthreads();
        if (t < 256) sc[t] += add;
        __syncthreads();
    }
    if (t < 256) {
        int rs = rb0 + sc[t] - dv;  // exclusive
        if (node < N) row_start[node] = rs;
        cur[t] = rs;
        dl[t] = (node < N) ? dis[node] : 0.f;
        wsum[t] = 0.f;
    }
    if (b == 0 && t == 0) row_start[N] = E;
    __syncthreads();
    // scatter to final CSR
    for (int i = rb0 + t; i < rb1; i += 512) {
        int v2 = staged[i];
        int sidx = v2 & 131071;
        int dloc = v2 >> 17;
        float w = dis[sidx] * dl[dloc];
        int pos = atomicAdd(&cur[dloc], 1);
        __half2 wh = __floats2half2_rn(w, w);
        csr[pos] = make_int2(sidx, *(int*)&wh);
        atomicAdd(&wsum[dloc], w);
    }
    __syncthreads();
    if (t < 256 && node < N) rowsum[node] = wsum[t] + dl[t] * dl[t];
}

// ---------------- fused agg64 + MFMA dense chain (r5/r8 config — best measured) ----------------
// block = 32 nodes, 4 waves. Phase 1: 8 threads per node (nl=t>>3, l=t&7 feature float4),
// all 32 nodes' gather chains concurrent. Phase 2: dense chain via MFMA.
#define NB 32
__global__ __launch_bounds__(256, 6)
void agg64_dense_kernel(const __half* __restrict__ mean16,
                        const int* __restrict__ row_start,
                        const int2* __restrict__ csr,
                        const float* __restrict__ dis,
                        const float* __restrict__ rowsum,
                        const _Float16* __restrict__ Wf16t,  // [128][64]
                        const float* __restrict__ bf,
                        const float* __restrict__ b1,
                        const _Float16* __restrict__ W2t,    // [128][128]
                        __half* __restrict__ h2, int N) {
    __shared__ _Float16 sagg[32][72];
    __shared__ _Float16 sx1[32][136];
    __shared__ float srs[32];
    int t = threadIdx.x;
    int nb0 = blockIdx.x * NB;
    const float4* m4 = (const float4*)mean16;  // row = 8 float4 (64 halfs)

    if (t < 32) srs[t] = (nb0 + t < N) ? rowsum[nb0 + t] : 0.f;

    // ---- phase 1: gather, 8 threads per node, 32 nodes in parallel ----
    {
        int nl = t >> 3;   // node_local 0..31
        int l = t & 7;     // feature float4 block 0..7
        int node = nb0 + nl;
        __half2 a0, a1, a2, a3;
        a0 = a1 = a2 = a3 = __floats2half2_rn(0.f, 0.f);
        if (node < N) {
            int beg = row_start[node];
            int end = row_start[node + 1];
            float d = dis[node];
            {
                float4 raw = m4[(size_t)node * 8 + l];
                const __half2* hp = (const __half2*)&raw;
                float d2f = d * d;
                __half2 d2h = __floats2half2_rn(d2f, d2f);
                a0 = __hmul2(hp[0], d2h); a1 = __hmul2(hp[1], d2h);
                a2 = __hmul2(hp[2], d2h); a3 = __hmul2(hp[3], d2h);
            }
            int k = beg;
            int kfull = beg + ((end - beg) & ~7);
            for (; k < kfull; k += 8) {  // unguarded: 8 edges, all in flight
                int2 e[8];
                float4 v[8];
#pragma unroll
                for (int m = 0; m < 8; m++) e[m] = csr[k + m];
#pragma unroll
                for (int m = 0; m < 8; m++) v[m] = m4[(size_t)e[m].x * 8 + l];
#pragma unroll
                for (int m = 0; m < 8; m++) {
                    __half2 wh = *(__half2*)&e[m].y;
                    const __half2* hp = (const __half2*)&v[m];
                    a0 = __hfma2(hp[0], wh, a0);
                    a1 = __hfma2(hp[1], wh, a1);
                    a2 = __hfma2(hp[2], wh, a2);
                    a3 = __hfma2(hp[3], wh, a3);
                }
            }
            if (k < end) {  // single guarded round of 8
                int2 e[8];
                float4 v[8];
#pragma unroll
                for (int m = 0; m < 8; m++) {
                    int kk = k + m;
                    e[m] = (kk < end) ? csr[kk] : make_int2(0, 0);  // wh=0 => no-op
                }
#pragma unroll
                for (int m = 0; m < 8; m++) v[m] = m4[(size_t)e[m].x * 8 + l];
#pragma unroll
                for (int m = 0; m < 8; m++) {
                    __half2 wh = *(__half2*)&e[m].y;
                    const __half2* hp = (const __half2*)&v[m];
                    a0 = __hfma2(hp[0], wh, a0);
                    a1 = __hfma2(hp[1], wh, a1);
                    a2 = __hfma2(hp[2], wh, a2);
                    a3 = __hfma2(hp[3], wh, a3);
                }
            }
        }
        float4 packed;
        __half2* pp = (__half2*)&packed;
        pp[0] = a0; pp[1] = a1; pp[2] = a2; pp[3] = a3;
        *(float4*)(&sagg[nl][l * 8]) = packed;
    }
    __syncthreads();

    // ---- phase 2: MFMA dense chain ----
    int wv = t >> 6, lane = t & 63;
    int rh = wv & 1;
    int ncb = (wv >> 1) * 64;
    int m16 = lane & 15;
    int qq = lane >> 4;

    f32x4 c0 = {}, c1 = {}, c2 = {}, c3 = {};
#pragma unroll
    for (int ks = 0; ks < 2; ks++) {
        int k0 = ks * 32 + qq * 8;
        f16x8 afrag = *(const f16x8*)(&sagg[rh * 16 + m16][k0]);
        f16x8 b0 = *(const f16x8*)(Wf16t + (size_t)(ncb + 0 * 16 + m16) * 64 + k0);
        f16x8 b1f = *(const f16x8*)(Wf16t + (size_t)(ncb + 1 * 16 + m16) * 64 + k0);
        f16x8 b2f = *(const f16x8*)(Wf16t + (size_t)(ncb + 2 * 16 + m16) * 64 + k0);
        f16x8 b3f = *(const f16x8*)(Wf16t + (size_t)(ncb + 3 * 16 + m16) * 64 + k0);
        c0 = __builtin_amdgcn_mfma_f32_16x16x32_f16(afrag, b0, c0, 0, 0, 0);
        c1 = __builtin_amdgcn_mfma_f32_16x16x32_f16(afrag, b1f, c1, 0, 0, 0);
        c2 = __builtin_amdgcn_mfma_f32_16x16x32_f16(afrag, b2f, c2, 0, 0, 0);
        c3 = __builtin_amdgcn_mfma_f32_16x16x32_f16(afrag, b3f, c3, 0, 0, 0);
    }
    {
        f32x4 cc[4] = {c0, c1, c2, c3};
#pragma unroll
        for (int nt = 0; nt < 4; nt++) {
            int ncol = ncb + nt * 16 + m16;
            float bfj = bf[ncol], b1j = b1[ncol];
#pragma unroll
            for (int r = 0; r < 4; r++) {
                int mrow = qq * 4 + r;
                float z = cc[nt][r] + srs[rh * 16 + mrow] * bfj + b1j;
                sx1[rh * 16 + mrow][ncol] = (_Float16)fmaxf(z, 0.f);
            }
        }
    }
    __syncthreads();

    f32x4 d0 = {}, d1 = {}, d2 = {}, d3 = {};
#pragma unroll
    for (int ks = 0; ks < 4; ks++) {
        int k0 = ks * 32 + qq * 8;
        f16x8 afrag = *(const f16x8*)(&sx1[rh * 16 + m16][k0]);
        f16x8 b0 = *(const f16x8*)(W2t + (size_t)(ncb + 0 * 16 + m16) * 128 + k0);
        f16x8 b1f = *(const f16x8*)(W2t + (size_t)(ncb + 1 * 16 + m16) * 128 + k0);
        f16x8 b2f = *(const f16x8*)(W2t + (size_t)(ncb + 2 * 16 + m16) * 128 + k0);
        f16x8 b3f = *(const f16x8*)(W2t + (size_t)(ncb + 3 * 16 + m16) * 128 + k0);
        d0 = __builtin_amdgcn_mfma_f32_16x16x32_f16(afrag, b0, d0, 0, 0, 0);
        d1 = __builtin_amdgcn_mfma_f32_16x16x32_f16(afrag, b1f, d1, 0, 0, 0);
        d2 = __builtin_amdgcn_mfma_f32_16x16x32_f16(afrag, b2f, d2, 0, 0, 0);
        d3 = __builtin_amdgcn_mfma_f32_16x16x32_f16(afrag, b3f, d3, 0, 0, 0);
    }
    {
        f32x4 dd[4] = {d0, d1, d2, d3};
#pragma unroll
        for (int nt = 0; nt < 4; nt++) {
            int ncol = ncb + nt * 16 + m16;
#pragma unroll
            for (int r = 0; r < 4; r++) {
                int node = nb0 + rh * 16 + qq * 4 + r;
                if (node < N) h2[(size_t)node * 128 + ncol] = __float2half(dd[nt][r]);
            }
        }
    }
}

// ---------------- layer 2: agg128 fp16 packed accumulate, 1 wave/node, 4 rows per gather ----------------
// lane (q,l): q=j>>4 edge slot (4), l=j&15 feature block (float4 = 4 half2)
__global__ __launch_bounds__(256, 8)
void gcn_agg128_kernel(const __half* __restrict__ hsrc,
                       const int* __restrict__ row_start,
                       const int2* __restrict__ csr,
                       const float* __restrict__ dis,
                       const float* __restrict__ b2,
                       __half* __restrict__ outx, int N) {
    int t = threadIdx.x;
    int w = t >> 6, j = t & 63;
    int q = j >> 4, l = j & 15;
    int node = blockIdx.x * 4 + w;
    if (node >= N) return;
    const float4* h4 = (const float4*)hsrc;  // row = 16 float4 (128 halfs)
    int beg = row_start[node];
    int end = row_start[node + 1];
    float d = dis[node];
    __half2 a0, a1, a2, a3;
    {
        float4 raw = h4[(size_t)node * 16 + l];
        const __half2* hp = (const __half2*)&raw;
        float d2f = d * d * ((q == 0) ? 1.f : 0.f);
        __half2 d2h = __floats2half2_rn(d2f, d2f);
        a0 = __hmul2(hp[0], d2h); a1 = __hmul2(hp[1], d2h);
        a2 = __hmul2(hp[2], d2h); a3 = __hmul2(hp[3], d2h);
    }
    int k = beg;
    int kfull = beg + ((end - beg) & ~31);
    for (; k < kfull; k += 32) {  // unguarded: 8 batches x 4 slots
        int2 e[8];
        float4 v[8];
#pragma unroll
        for (int m = 0; m < 8; m++) e[m] = csr[k + 4 * m + q];
#pragma unroll
        for (int m = 0; m < 8; m++) v[m] = h4[(size_t)e[m].x * 16 + l];
#pragma unroll
        for (int m = 0; m < 8; m++) {
            __half2 wh = *(__half2*)&e[m].y;
            const __half2* hp = (const __half2*)&v[m];
            a0 = __hfma2(hp[0], wh, a0);
            a1 = __hfma2(hp[1], wh, a1);
            a2 = __hfma2(hp[2], wh, a2);
            a3 = __hfma2(hp[3], wh, a3);
        }
    }
    if (k < end) {  // single guarded round: 8 batches x 4 slots = 32 edges
        int2 e[8];
        float4 v[8];
#pragma unroll
        for (int m = 0; m < 8; m++) {
            int kk = k + 4 * m + q;
            e[m] = (kk < end) ? csr[kk] : make_int2(0, 0);  // wh=0 => no-op
        }
#pragma unroll
        for (int m = 0; m < 8; m++) v[m] = h4[(size_t)e[m].x * 16 + l];
#pragma unroll
        for (int m = 0; m < 8; m++) {
            __half2 wh = *(__half2*)&e[m].y;
            const __half2* hp = (const __half2*)&v[m];
            a0 = __hfma2(hp[0], wh, a0);
            a1 = __hfma2(hp[1], wh, a1);
            a2 = __hfma2(hp[2], wh, a2);
            a3 = __hfma2(hp[3], wh, a3);
        }
    }
    // fold across q (lane bits 4,5)
#pragma unroll
    for (int mask = 16; mask <= 32; mask <<= 1) {
        a0 = __hadd2(a0, shfl_xor_h2(a0, mask));
        a1 = __hadd2(a1, shfl_xor_h2(a1, mask));
        a2 = __hadd2(a2, shfl_xor_h2(a2, mask));
        a3 = __hadd2(a3, shfl_xor_h2(a3, mask));
    }
    if (q == 0) {
        // fp32 epilogue: + b2, relu, pack fp16
        float2 f0 = __half22float2(a0), f1 = __half22float2(a1);
        float2 f2 = __half22float2(a2), f3 = __half22float2(a3);
        const float4* b4 = (const float4*)b2;
        float4 ba = b4[l * 2], bb = b4[l * 2 + 1];
        __half2 o0 = __floats2half2_rn(fmaxf(f0.x + ba.x, 0.f), fmaxf(f0.y + ba.y, 0.f));
        __half2 o1 = __floats2half2_rn(fmaxf(f1.x + ba.z, 0.f), fmaxf(f1.y + ba.w, 0.f));
        __half2 o2 = __floats2half2_rn(fmaxf(f2.x + bb.x, 0.f), fmaxf(f2.y + bb.y, 0.f));
        __half2 o3 = __floats2half2_rn(fmaxf(f3.x + bb.z, 0.f), fmaxf(f3.y + bb.w, 0.f));
        float4 packed;
        __half2* pp = (__half2*)&packed;
        pp[0] = o0; pp[1] = o1; pp[2] = o2; pp[3] = o3;
        ((float4*)outx)[(size_t)node * 16 + l] = packed;
    }
}

// ---------------- fused pool + head: one block (256 threads, 4 row-waves) per graph ----------------
__device__ __forceinline__ int lower_bound_i(const int* __restrict__ a, int n, int val) {
    int lo = 0, hi = n;
    while (lo < hi) {
        int mid = (lo + hi) >> 1;
        if (a[mid] < val) lo = mid + 1; else hi = mid;
    }
    return lo;
}

__global__ void pool_head_kernel(const __half* __restrict__ x,
                                 const int* __restrict__ batch,
                                 const float* __restrict__ Wfc,
                                 const float* __restrict__ bfc,
                                 const float* __restrict__ Wout,
                                 const float* __restrict__ bout,
                                 float* __restrict__ out, int N) {
    int gr = blockIdx.x;
    int t = threadIdx.x;  // 0..255
    int j2 = t & 63, w = t >> 6;  // 4 row-waves
    __shared__ float2 spart[4][64];
    __shared__ float sg[128];
    __shared__ float sfc[2][128];
    __shared__ float sred[128];
    int beg = lower_bound_i(batch, N, gr);
    int end = lower_bound_i(batch, N, gr + 1);
    const __half2* x2 = (const __half2*)x;  // row stride 64 half2
    float2 acc = make_float2(0.f, 0.f);
    for (int i = beg + w; i < end; i += 4) {
        float2 a = __half22float2(x2[(size_t)i * 64 + j2]);
        acc.x += a.x; acc.y += a.y;
    }
    spart[w][j2] = acc;
    __syncthreads();
    if (t < 64) {
        float inv = 1.0f / fmaxf((float)(end - beg), 1.0f);
        float2 s0 = spart[0][t], s1 = spart[1][t];
        float2 s2 = spart[2][t], s3 = spart[3][t];
        sg[2 * t] = (s0.x + s1.x + s2.x + s3.x) * inv;
        sg[2 * t + 1] = (s0.y + s1.y + s2.y + s3.y) * inv;
    }
    __syncthreads();
    // FC: 256 threads, output j = t&127, k-half = t>>7
    int j = t & 127, hb = t >> 7;
    float a = 0.f;
#pragma unroll
    for (int k = 0; k < 64; k++) a += sg[hb * 64 + k] * Wfc[(hb * 64 + k) * 128 + j];
    sfc[hb][j] = a;
    __syncthreads();
    if (t < 128) {
        float aa = sfc[0][t] + sfc[1][t] + bfc[t];
        float f = fmaxf(aa, 0.f);
        sred[t] = f * Wout[t];
    }
    __syncthreads();
    if (t < 64) {
        float v = sred[t] + sred[t + 64];
#pragma unroll
        for (int off = 32; off > 0; off >>= 1) v += __shfl_down(v, off);
        if (t == 0) {
            float logit = v + bout[0];
            out[gr] = 1.0f / (1.0f + expf(-logit));
            out[NUM_GRAPHS + gr] = logit;
        }
    }
}

extern "C" void kernel_launch(void* const* d_in, const int* in_sizes, int n_in,
                              void* d_out, int out_size, void* d_ws, size_t ws_size,
                              hipStream_t stream) {
    const int* tok   = (const int*)d_in[0];
    const int* eidx  = (const int*)d_in[1];
    const int* batch = (const int*)d_in[2];
    const float* emb = (const float*)d_in[3];
    const float* Wp  = (const float*)d_in[4];
    const float* bp  = (const float*)d_in[5];
    const float* W1  = (const float*)d_in[6];
    const float* b1  = (const float*)d_in[7];
    const float* W2  = (const float*)d_in[8];
    const float* b2  = (const float*)d_in[9];
    const float* Wfc = (const float*)d_in[10];
    const float* bfc = (const float*)d_in[11];
    const float* Wout= (const float*)d_in[12];
    const float* bout= (const float*)d_in[13];
    float* out = (float*)d_out;

    const int N = in_sizes[2];
    const int E = in_sizes[1] / 2;
    const int* src = eidx;
    const int* dst = eidx + E;
    const int Np = (N + 3) & ~3;
    const int nbuck = (N + 255) / 256;               // 391 for N=100k
    const int nchunk = (E + CHUNK - 1) / CHUNK;      // 196
    const int emb_n4 = in_sizes[3] / 4;              // float4 count of emb
    const int embB = (emb_n4 + 255) / 256;
    const int degB = (Np + 255) / 256;

    // workspace layout (float units)
    float* ws = (float*)d_ws;
    size_t off = 0;
    float* dis     = ws + off;            off += Np;
    __half* mean16 = (__half*)(ws + off); off += (size_t)Np * 32;
    __half* agg16  = (__half*)(ws + off); off += (size_t)Np * 32;  // hosts deg[] (int, Np)
    float* rowsum  = ws + off;            off += Np;
    __half* h2buf  = (__half*)(ws + off); off += (size_t)Np * 64;
    __half* xfin16 = (__half*)(ws + off); off += (size_t)Np * 64;
    __half* emb16  = (__half*)(ws + off); off += (size_t)(in_sizes[3] / 2 + 4);
    _Float16* Wf16t = (_Float16*)(ws + off); off += 4096;
    _Float16* W2t   = (_Float16*)(ws + off); off += 8192;
    float* bf      = ws + off;            off += 128;
    int* row_start = (int*)(ws + off);    off += Np + 4;
    int* staged    = (int*)(ws + off);    off += E;
    int* total     = (int*)(ws + off);    off += NBUCK_MAX;
    int* bucket_base   = (int*)(ws + off); off += NBUCK_MAX + 8;  // unused (layout stability)
    int2* csr      = (int2*)(ws + off);   // E int2
    (void)bucket_base;
    int* deg = (int*)agg16;  // deg[] lives in the (otherwise dead) agg16 region
    // hist2d / chunkbase alias h2buf: only live during the sort pipeline, h2buf is
    // first written by agg64_dense_kernel which runs strictly after csr_merged.
    int* hist2d    = (int*)h2buf;                        // [nchunk][NBUCK_MAX]
    int* chunkbase = hist2d + (size_t)nchunk * NBUCK_MAX;  // [nchunk][NBUCK_MAX]

    // --- fused weight prep + emb fp16 conversion + deg zero (one launch) ---
    prep_fused_kernel<<<128 + embB + degB, 256, 0, stream>>>(
        Wp, W1, W2, bp, emb, Wf16t, W2t, bf, emb16, emb_n4, embB, deg, Np);

    // --- combined: bucket hist (+ per-node deg atomics) + embed/token-mean ---
    hist_embed_kernel<<<nchunk + (N + 7) / 8, 512, 0, stream>>>(
        dst, hist2d, E, nbuck, nchunk, deg, tok, emb16, mean16, N);

    // --- per-bucket chunk scan -> chunkbase, total; + dis from deg ---
    chunk_scan_kernel<<<nbuck, 64, 0, stream>>>(hist2d, chunkbase, total, nchunk,
                                                deg, dis, N);

    // --- one-pass scatter (derives bucket_base in-LDS) ---
    binscatter_kernel<<<nchunk, 512, 0, stream>>>(src, dst, total, chunkbase,
                                                  staged, E, nbuck);

    // --- merged: row_start from deg + final CSR + rowsum (replaces bucket_count+csr_write) ---
    csr_merged_kernel<<<nbuck, 512, 0, stream>>>(staged, total, deg, dis, row_start,
                                                 csr, rowsum, N, E, nbuck);

    // --- fused: 64-dim aggregate (8 thr/node) + MFMA dense chain -> h2buf ---
    agg64_dense_kernel<<<(N + NB - 1) / NB, 256, 0, stream>>>(mean16, row_start, csr, dis,
                                                              rowsum, Wf16t, bf, b1, W2t,
                                                              h2buf, N);

    // --- layer 2 aggregate (fp16 packed, 1 wave/node, wide tail) + b2 + ReLU -> xfin16 ---
    gcn_agg128_kernel<<<(N + 3) / 4, 256, 0, stream>>>(h2buf, row_start, csr, dis, b2,
                                                       xfin16, N);

    // --- fused global mean pool + head ---
    pool_head_kernel<<<NUM_GRAPHS, 256, 0, stream>>>(xfin16, batch, Wfc, bfc, Wout, bout,
                                                     out, N);
}

// Round 10
// 308.278 us; speedup vs baseline: 1.1670x; 1.1670x over previous
//
#include <hip/hip_runtime.h>
#include <hip/hip_bf16.h>
#include <hip/hip_fp16.h>
#include <math.h>

#define N_TOKENS 16
#define TOK_DIM 64
#define NODE_DIM 64
#define HID 128
#define FC 128
#define NUM_GRAPHS 1024
#define NBUCK_MAX 512
#define CHUNK 8192

typedef _Float16 f16x8 __attribute__((ext_vector_type(8)));
typedef float f32x4 __attribute__((ext_vector_type(4)));

__device__ __forceinline__ __half2 shfl_xor_h2(__half2 v, int mask) {
    int i = *(int*)&v;
    i = __shfl_xor(i, mask);
    return *(__half2*)&i;
}

// ---------------- fused prep: weights (blocks 0..127) + emb fp32->fp16 (rest) ----------------
__global__ void prep_fused_kernel(const float* __restrict__ Wp, const float* __restrict__ W1,
                                  const float* __restrict__ W2, const float* __restrict__ bp,
                                  const float* __restrict__ emb,
                                  _Float16* __restrict__ Wf16t, _Float16* __restrict__ W2t,
                                  float* __restrict__ bf, __half* __restrict__ emb16, int n4) {
    int b = blockIdx.x;
    int t = threadIdx.x;
    if (b < 128) {
        int n = b;
        if (t < 64) {
            float acc = 0.f;
#pragma unroll
            for (int d = 0; d < 64; d++) acc += Wp[t * 64 + d] * W1[d * 128 + n];
            Wf16t[(size_t)n * 64 + t] = (_Float16)acc;
        } else if (t < 128) {
            int d = t - 64;  // lane of wave 1
            float v = bp[d] * W1[d * 128 + n];
#pragma unroll
            for (int off = 32; off > 0; off >>= 1) v += __shfl_down(v, off);
            if (d == 0) bf[n] = v;
        }
        if (t < 128) W2t[(size_t)n * 128 + t] = (_Float16)W2[(size_t)t * 128 + n];
    } else {
        int i = (b - 128) * 256 + t;
        if (i < n4) {
            float4 v = ((const float4*)emb)[i];
            __half2 h0 = __floats2half2_rn(v.x, v.y);
            __half2 h1 = __floats2half2_rn(v.z, v.w);
            float2 p;
            ((__half2*)&p)[0] = h0;
            ((__half2*)&p)[1] = h1;
            ((float2*)emb16)[i] = p;
        }
    }
}

// ---------------- combined: bucket hist (blocks 0..nchunk-1) + embed/token-mean (rest) ----------------
// hist: per-chunk per-bucket counts -> hist2d[chunk][bucket]
// embed: 512 thr = 8 nodes/block; lane (q,l): q=j>>3 token slot, l=j&7 feature float4
__global__ void hist_embed_kernel(const int* __restrict__ dst, int* __restrict__ hist2d,
                                  int E, int nbuck, int nchunk,
                                  const int* __restrict__ tok,
                                  const __half* __restrict__ emb16,
                                  __half* __restrict__ mean16, int N) {
    int b = blockIdx.x;
    int t = threadIdx.x;
    if (b < nchunk) {
        __shared__ int h[NBUCK_MAX];
        for (int i = t; i < nbuck; i += 512) h[i] = 0;
        __syncthreads();
        int base = b * CHUNK;
        for (int i = t; i < CHUNK; i += 512) {
            int e = base + i;
            if (e < E) atomicAdd(&h[dst[e] >> 8], 1);
        }
        __syncthreads();
        int* row = hist2d + (size_t)b * NBUCK_MAX;
        for (int i = t; i < nbuck; i += 512) row[i] = h[i];
    } else {
        int w = t >> 6, j = t & 63;
        int q = j >> 3, l = j & 7;
        int i = (b - nchunk) * 8 + w;
        if (i >= N) return;
        const float4* e4 = (const float4*)emb16;  // row = 8 float4 (64 halfs)
        int t0 = tok[i * 16 + q];
        int t1 = tok[i * 16 + q + 8];
        float4 v0 = e4[(size_t)t0 * 8 + l];
        float4 v1 = e4[(size_t)t1 * 8 + l];
        const __half2* p0 = (const __half2*)&v0;
        const __half2* p1 = (const __half2*)&v1;
        __half2 a0 = __hadd2(p0[0], p1[0]);
        __half2 a1 = __hadd2(p0[1], p1[1]);
        __half2 a2 = __hadd2(p0[2], p1[2]);
        __half2 a3 = __hadd2(p0[3], p1[3]);
#pragma unroll
        for (int mask = 8; mask <= 32; mask <<= 1) {
            a0 = __hadd2(a0, shfl_xor_h2(a0, mask));
            a1 = __hadd2(a1, shfl_xor_h2(a1, mask));
            a2 = __hadd2(a2, shfl_xor_h2(a2, mask));
            a3 = __hadd2(a3, shfl_xor_h2(a3, mask));
        }
        if (q == 0) {
            __half2 inv = __floats2half2_rn(1.0f / 16.0f, 1.0f / 16.0f);
            float4 packed;
            __half2* pp = (__half2*)&packed;
            pp[0] = __hmul2(a0, inv);
            pp[1] = __hmul2(a1, inv);
            pp[2] = __hmul2(a2, inv);
            pp[3] = __hmul2(a3, inv);
            ((float4*)mean16)[(size_t)i * 8 + l] = packed;
        }
    }
}

// per-bucket exclusive scan over chunks -> chunkbase[chunk][bucket], total[bucket]
// grid = nbuck blocks x 64 threads (one wave each)
__global__ void chunk_scan_kernel(const int* __restrict__ hist2d, int* __restrict__ chunkbase,
                                  int* __restrict__ total, int nchunk) {
    int b = blockIdx.x;
    int lane = threadIdx.x;  // 0..63
    int run = 0;
    for (int c0 = 0; c0 < nchunk; c0 += 64) {
        int c = c0 + lane;
        int v = (c < nchunk) ? hist2d[(size_t)c * NBUCK_MAX + b] : 0;
        int s = v;
#pragma unroll
        for (int off = 1; off < 64; off <<= 1) {
            int u = __shfl_up(s, off);
            if (lane >= off) s += u;
        }
        if (c < nchunk) chunkbase[(size_t)c * NBUCK_MAX + b] = s - v + run;
        run += __shfl(s, 63);
    }
    if (lane == 0) total[b] = run;
}

// one-pass scatter; each block re-derives bucket_base from total[] via LDS scan
// (block 0 publishes bucket_base for downstream kernels). packed val = src | (dst&255)<<17
__global__ void binscatter_kernel(const int* __restrict__ src, const int* __restrict__ dst,
                                  const int* __restrict__ total,
                                  const int* __restrict__ chunkbase,
                                  int* __restrict__ bucket_base,
                                  int* __restrict__ staged, int E, int nbuck) {
    __shared__ int s[512];
    __shared__ int h[NBUCK_MAX];
    int t = threadIdx.x;
    int v = (t < nbuck) ? total[t] : 0;
    s[t] = v;
    __syncthreads();
    for (int off = 1; off < 512; off <<= 1) {
        int add = (t >= off) ? s[t - off] : 0;
        __syncthreads();
        s[t] += add;
        __syncthreads();
    }
    const int* cb = chunkbase + (size_t)blockIdx.x * NBUCK_MAX;
    if (t < nbuck) h[t] = (s[t] - v) + cb[t];
    if (blockIdx.x == 0) {
        if (t < nbuck) bucket_base[t] = s[t] - v;
        if (t == 511) bucket_base[nbuck] = s[511];
    }
    __syncthreads();
    int base = blockIdx.x * CHUNK;
    for (int i = t; i < CHUNK; i += 512) {
        int e = base + i;
        if (e < E) {
            int d = dst[e], sv = src[e];
            int b = d >> 8;
            int r = atomicAdd(&h[b], 1);
            staged[r] = sv | ((d & 255) << 17);
        }
    }
}

// per bucket: per-node degree -> row_start + dis (coalesced writes)
__global__ void bucket_count_kernel(const int* __restrict__ staged,
                                    const int* __restrict__ bucket_base,
                                    int* __restrict__ row_start, float* __restrict__ dis,
                                    int N, int E) {
    __shared__ int cnt[256];
    __shared__ int sc[256];
    int b = blockIdx.x;
    int t = threadIdx.x;
    cnt[t] = 0;
    __syncthreads();
    int rb0 = bucket_base[b], rb1 = bucket_base[b + 1];
    for (int i = rb0 + t; i < rb1; i += 256) atomicAdd(&cnt[staged[i] >> 17], 1);
    __syncthreads();
    int v = cnt[t];
    sc[t] = v;
    __syncthreads();
    for (int off = 1; off < 256; off <<= 1) {
        int add = (t >= off) ? sc[t - off] : 0;
        __syncthreads();
        sc[t] += add;
        __syncthreads();
    }
    int node = b * 256 + t;
    if (node < N) {
        row_start[node] = rb0 + sc[t] - v;  // exclusive
        dis[node] = rsqrtf(1.0f + (float)v);  // +1 self loop
    }
    if (b == 0 && t == 0) row_start[N] = E;
}

// per bucket: final CSR (src, half2(w,w)) + rowsum — block-local contiguous region
__global__ void csr_write_kernel(const int* __restrict__ staged,
                                 const int* __restrict__ bucket_base,
                                 const int* __restrict__ row_start,
                                 const float* __restrict__ dis,
                                 int2* __restrict__ csr, float* __restrict__ rowsum, int N) {
    __shared__ int cur[256];
    __shared__ float dl[256];
    __shared__ float wsum[256];
    int b = blockIdx.x;
    int t = threadIdx.x;
    int node = b * 256 + t;
    cur[t] = (node < N) ? row_start[node] : 0;
    dl[t] = (node < N) ? dis[node] : 0.f;
    wsum[t] = 0.f;
    __syncthreads();
    int rb0 = bucket_base[b], rb1 = bucket_base[b + 1];
    for (int i = rb0 + t; i < rb1; i += 256) {
        int v = staged[i];
        int s = v & 131071;
        int dloc = v >> 17;
        float w = dis[s] * dl[dloc];
        int pos = atomicAdd(&cur[dloc], 1);
        __half2 wh = __floats2half2_rn(w, w);
        csr[pos] = make_int2(s, *(int*)&wh);
        atomicAdd(&wsum[dloc], w);
    }
    __syncthreads();
    if (node < N) rowsum[node] = wsum[t] + dl[t] * dl[t];
}

// ---------------- fused agg64 + MFMA dense chain (r8 config, launch_bounds 6->4) ----------------
// block = 32 nodes, 4 waves. Phase 1: 8 threads per node (nl=t>>3, l=t&7 feature float4),
// all 32 nodes' gather chains concurrent. launch_bounds(256,4) gives the allocator room
// to keep the e[8]+v[8] batch (~48 regs) fully live — r8's VGPR=32 partially serialized
// the 8-load batch (r6 proved register starvation is catastrophic for this gather).
// Phase 2: dense chain via MFMA.
#define NB 32
__global__ __launch_bounds__(256, 4)
void agg64_dense_kernel(const __half* __restrict__ mean16,
                        const int* __restrict__ row_start,
                        const int2* __restrict__ csr,
                        const float* __restrict__ dis,
                        const float* __restrict__ rowsum,
                        const _Float16* __restrict__ Wf16t,  // [128][64]
                        const float* __restrict__ bf,
                        const float* __restrict__ b1,
                        const _Float16* __restrict__ W2t,    // [128][128]
                        __half* __restrict__ h2, int N) {
    __shared__ _Float16 sagg[32][72];
    __shared__ _Float16 sx1[32][136];
    __shared__ float srs[32];
    int t = threadIdx.x;
    int nb0 = blockIdx.x * NB;
    const float4* m4 = (const float4*)mean16;  // row = 8 float4 (64 halfs)

    if (t < 32) srs[t] = (nb0 + t < N) ? rowsum[nb0 + t] : 0.f;

    // ---- phase 1: gather, 8 threads per node, 32 nodes in parallel ----
    {
        int nl = t >> 3;   // node_local 0..31
        int l = t & 7;     // feature float4 block 0..7
        int node = nb0 + nl;
        __half2 a0, a1, a2, a3;
        a0 = a1 = a2 = a3 = __floats2half2_rn(0.f, 0.f);
        if (node < N) {
            int beg = row_start[node];
            int end = row_start[node + 1];
            float d = dis[node];
            {
                float4 raw = m4[(size_t)node * 8 + l];
                const __half2* hp = (const __half2*)&raw;
                float d2f = d * d;
                __half2 d2h = __floats2half2_rn(d2f, d2f);
                a0 = __hmul2(hp[0], d2h); a1 = __hmul2(hp[1], d2h);
                a2 = __hmul2(hp[2], d2h); a3 = __hmul2(hp[3], d2h);
            }
            int k = beg;
            int kfull = beg + ((end - beg) & ~7);
            for (; k < kfull; k += 8) {  // unguarded: 8 edges, all in flight
                int2 e[8];
                float4 v[8];
#pragma unroll
                for (int m = 0; m < 8; m++) e[m] = csr[k + m];
#pragma unroll
                for (int m = 0; m < 8; m++) v[m] = m4[(size_t)e[m].x * 8 + l];
#pragma unroll
                for (int m = 0; m < 8; m++) {
                    __half2 wh = *(__half2*)&e[m].y;
                    const __half2* hp = (const __half2*)&v[m];
                    a0 = __hfma2(hp[0], wh, a0);
                    a1 = __hfma2(hp[1], wh, a1);
                    a2 = __hfma2(hp[2], wh, a2);
                    a3 = __hfma2(hp[3], wh, a3);
                }
            }
            if (k < end) {  // single guarded round of 8
                int2 e[8];
                float4 v[8];
#pragma unroll
                for (int m = 0; m < 8; m++) {
                    int kk = k + m;
                    e[m] = (kk < end) ? csr[kk] : make_int2(0, 0);  // wh=0 => no-op
                }
#pragma unroll
                for (int m = 0; m < 8; m++) v[m] = m4[(size_t)e[m].x * 8 + l];
#pragma unroll
                for (int m = 0; m < 8; m++) {
                    __half2 wh = *(__half2*)&e[m].y;
                    const __half2* hp = (const __half2*)&v[m];
                    a0 = __hfma2(hp[0], wh, a0);
                    a1 = __hfma2(hp[1], wh, a1);
                    a2 = __hfma2(hp[2], wh, a2);
                    a3 = __hfma2(hp[3], wh, a3);
                }
            }
        }
        float4 packed;
        __half2* pp = (__half2*)&packed;
        pp[0] = a0; pp[1] = a1; pp[2] = a2; pp[3] = a3;
        *(float4*)(&sagg[nl][l * 8]) = packed;
    }
    __syncthreads();

    // ---- phase 2: MFMA dense chain ----
    int wv = t >> 6, lane = t & 63;
    int rh = wv & 1;
    int ncb = (wv >> 1) * 64;
    int m16 = lane & 15;
    int qq = lane >> 4;

    f32x4 c0 = {}, c1 = {}, c2 = {}, c3 = {};
#pragma unroll
    for (int ks = 0; ks < 2; ks++) {
        int k0 = ks * 32 + qq * 8;
        f16x8 afrag = *(const f16x8*)(&sagg[rh * 16 + m16][k0]);
        f16x8 b0 = *(const f16x8*)(Wf16t + (size_t)(ncb + 0 * 16 + m16) * 64 + k0);
        f16x8 b1f = *(const f16x8*)(Wf16t + (size_t)(ncb + 1 * 16 + m16) * 64 + k0);
        f16x8 b2f = *(const f16x8*)(Wf16t + (size_t)(ncb + 2 * 16 + m16) * 64 + k0);
        f16x8 b3f = *(const f16x8*)(Wf16t + (size_t)(ncb + 3 * 16 + m16) * 64 + k0);
        c0 = __builtin_amdgcn_mfma_f32_16x16x32_f16(afrag, b0, c0, 0, 0, 0);
        c1 = __builtin_amdgcn_mfma_f32_16x16x32_f16(afrag, b1f, c1, 0, 0, 0);
        c2 = __builtin_amdgcn_mfma_f32_16x16x32_f16(afrag, b2f, c2, 0, 0, 0);
        c3 = __builtin_amdgcn_mfma_f32_16x16x32_f16(afrag, b3f, c3, 0, 0, 0);
    }
    {
        f32x4 cc[4] = {c0, c1, c2, c3};
#pragma unroll
        for (int nt = 0; nt < 4; nt++) {
            int ncol = ncb + nt * 16 + m16;
            float bfj = bf[ncol], b1j = b1[ncol];
#pragma unroll
            for (int r = 0; r < 4; r++) {
                int mrow = qq * 4 + r;
                float z = cc[nt][r] + srs[rh * 16 + mrow] * bfj + b1j;
                sx1[rh * 16 + mrow][ncol] = (_Float16)fmaxf(z, 0.f);
            }
        }
    }
    __syncthreads();

    f32x4 d0 = {}, d1 = {}, d2 = {}, d3 = {};
#pragma unroll
    for (int ks = 0; ks < 4; ks++) {
        int k0 = ks * 32 + qq * 8;
        f16x8 afrag = *(const f16x8*)(&sx1[rh * 16 + m16][k0]);
        f16x8 b0 = *(const f16x8*)(W2t + (size_t)(ncb + 0 * 16 + m16) * 128 + k0);
        f16x8 b1f = *(const f16x8*)(W2t + (size_t)(ncb + 1 * 16 + m16) * 128 + k0);
        f16x8 b2f = *(const f16x8*)(W2t + (size_t)(ncb + 2 * 16 + m16) * 128 + k0);
        f16x8 b3f = *(const f16x8*)(W2t + (size_t)(ncb + 3 * 16 + m16) * 128 + k0);
        d0 = __builtin_amdgcn_mfma_f32_16x16x32_f16(afrag, b0, d0, 0, 0, 0);
        d1 = __builtin_amdgcn_mfma_f32_16x16x32_f16(afrag, b1f, d1, 0, 0, 0);
        d2 = __builtin_amdgcn_mfma_f32_16x16x32_f16(afrag, b2f, d2, 0, 0, 0);
        d3 = __builtin_amdgcn_mfma_f32_16x16x32_f16(afrag, b3f, d3, 0, 0, 0);
    }
    {
        f32x4 dd[4] = {d0, d1, d2, d3};
#pragma unroll
        for (int nt = 0; nt < 4; nt++) {
            int ncol = ncb + nt * 16 + m16;
#pragma unroll
            for (int r = 0; r < 4; r++) {
                int node = nb0 + rh * 16 + qq * 4 + r;
                if (node < N) h2[(size_t)node * 128 + ncol] = __float2half(dd[nt][r]);
            }
        }
    }
}

// ---------------- layer 2: agg128 fp16 packed accumulate, 1 wave/node, 4 rows per gather ----------------
// lane (q,l): q=j>>4 edge slot (4), l=j&15 feature block (float4 = 4 half2)
__global__ __launch_bounds__(256, 8)
void gcn_agg128_kernel(const __half* __restrict__ hsrc,
                       const int* __restrict__ row_start,
                       const int2* __restrict__ csr,
                       const float* __restrict__ dis,
                       const float* __restrict__ b2,
                       __half* __restrict__ outx, int N) {
    int t = threadIdx.x;
    int w = t >> 6, j = t & 63;
    int q = j >> 4, l = j & 15;
    int node = blockIdx.x * 4 + w;
    if (node >= N) return;
    const float4* h4 = (const float4*)hsrc;  // row = 16 float4 (128 halfs)
    int beg = row_start[node];
    int end = row_start[node + 1];
    float d = dis[node];
    __half2 a0, a1, a2, a3;
    {
        float4 raw = h4[(size_t)node * 16 + l];
        const __half2* hp = (const __half2*)&raw;
        float d2f = d * d * ((q == 0) ? 1.f : 0.f);
        __half2 d2h = __floats2half2_rn(d2f, d2f);
        a0 = __hmul2(hp[0], d2h); a1 = __hmul2(hp[1], d2h);
        a2 = __hmul2(hp[2], d2h); a3 = __hmul2(hp[3], d2h);
    }
    int k = beg;
    int kfull = beg + ((end - beg) & ~31);
    for (; k < kfull; k += 32) {  // unguarded: 8 batches x 4 slots
        int2 e[8];
        float4 v[8];
#pragma unroll
        for (int m = 0; m < 8; m++) e[m] = csr[k + 4 * m + q];
#pragma unroll
        for (int m = 0; m < 8; m++) v[m] = h4[(size_t)e[m].x * 16 + l];
#pragma unroll
        for (int m = 0; m < 8; m++) {
            __half2 wh = *(__half2*)&e[m].y;
            const __half2* hp = (const __half2*)&v[m];
            a0 = __hfma2(hp[0], wh, a0);
            a1 = __hfma2(hp[1], wh, a1);
            a2 = __hfma2(hp[2], wh, a2);
            a3 = __hfma2(hp[3], wh, a3);
        }
    }
    if (k < end) {  // single guarded round: 8 batches x 4 slots = 32 edges
        int2 e[8];
        float4 v[8];
#pragma unroll
        for (int m = 0; m < 8; m++) {
            int kk = k + 4 * m + q;
            e[m] = (kk < end) ? csr[kk] : make_int2(0, 0);  // wh=0 => no-op
        }
#pragma unroll
        for (int m = 0; m < 8; m++) v[m] = h4[(size_t)e[m].x * 16 + l];
#pragma unroll
        for (int m = 0; m < 8; m++) {
            __half2 wh = *(__half2*)&e[m].y;
            const __half2* hp = (const __half2*)&v[m];
            a0 = __hfma2(hp[0], wh, a0);
            a1 = __hfma2(hp[1], wh, a1);
            a2 = __hfma2(hp[2], wh, a2);
            a3 = __hfma2(hp[3], wh, a3);
        }
    }
    // fold across q (lane bits 4,5)
#pragma unroll
    for (int mask = 16; mask <= 32; mask <<= 1) {
        a0 = __hadd2(a0, shfl_xor_h2(a0, mask));
        a1 = __hadd2(a1, shfl_xor_h2(a1, mask));
        a2 = __hadd2(a2, shfl_xor_h2(a2, mask));
        a3 = __hadd2(a3, shfl_xor_h2(a3, mask));
    }
    if (q == 0) {
        // fp32 epilogue: + b2, relu, pack fp16
        float2 f0 = __half22float2(a0), f1 = __half22float2(a1);
        float2 f2 = __half22float2(a2), f3 = __half22float2(a3);
        const float4* b4 = (const float4*)b2;
        float4 ba = b4[l * 2], bb = b4[l * 2 + 1];
        __half2 o0 = __floats2half2_rn(fmaxf(f0.x + ba.x, 0.f), fmaxf(f0.y + ba.y, 0.f));
        __half2 o1 = __floats2half2_rn(fmaxf(f1.x + ba.z, 0.f), fmaxf(f1.y + ba.w, 0.f));
        __half2 o2 = __floats2half2_rn(fmaxf(f2.x + bb.x, 0.f), fmaxf(f2.y + bb.y, 0.f));
        __half2 o3 = __floats2half2_rn(fmaxf(f3.x + bb.z, 0.f), fmaxf(f3.y + bb.w, 0.f));
        float4 packed;
        __half2* pp = (__half2*)&packed;
        pp[0] = o0; pp[1] = o1; pp[2] = o2; pp[3] = o3;
        ((float4*)outx)[(size_t)node * 16 + l] = packed;
    }
}

// ---------------- fused pool + head: one block (256 threads, 4 row-waves) per graph ----------------
__device__ __forceinline__ int lower_bound_i(const int* __restrict__ a, int n, int val) {
    int lo = 0, hi = n;
    while (lo < hi) {
        int mid = (lo + hi) >> 1;
        if (a[mid] < val) lo = mid + 1; else hi = mid;
    }
    return lo;
}

__global__ void pool_head_kernel(const __half* __restrict__ x,
                                 const int* __restrict__ batch,
                                 const float* __restrict__ Wfc,
                                 const float* __restrict__ bfc,
                                 const float* __restrict__ Wout,
                                 const float* __restrict__ bout,
                                 float* __restrict__ out, int N) {
    int gr = blockIdx.x;
    int t = threadIdx.x;  // 0..255
    int j2 = t & 63, w = t >> 6;  // 4 row-waves
    __shared__ float2 spart[4][64];
    __shared__ float sg[128];
    __shared__ float sfc[2][128];
    __shared__ float sred[128];
    int beg = lower_bound_i(batch, N, gr);
    int end = lower_bound_i(batch, N, gr + 1);
    const __half2* x2 = (const __half2*)x;  // row stride 64 half2
    float2 acc = make_float2(0.f, 0.f);
    for (int i = beg + w; i < end; i += 4) {
        float2 a = __half22float2(x2[(size_t)i * 64 + j2]);
        acc.x += a.x; acc.y += a.y;
    }
    spart[w][j2] = acc;
    __syncthreads();
    if (t < 64) {
        float inv = 1.0f / fmaxf((float)(end - beg), 1.0f);
        float2 s0 = spart[0][t], s1 = spart[1][t];
        float2 s2 = spart[2][t], s3 = spart[3][t];
        sg[2 * t] = (s0.x + s1.x + s2.x + s3.x) * inv;
        sg[2 * t + 1] = (s0.y + s1.y + s2.y + s3.y) * inv;
    }
    __syncthreads();
    // FC: 256 threads, output j = t&127, k-half = t>>7
    int j = t & 127, hb = t >> 7;
    float a = 0.f;
#pragma unroll
    for (int k = 0; k < 64; k++) a += sg[hb * 64 + k] * Wfc[(hb * 64 + k) * 128 + j];
    sfc[hb][j] = a;
    __syncthreads();
    if (t < 128) {
        float aa = sfc[0][t] + sfc[1][t] + bfc[t];
        float f = fmaxf(aa, 0.f);
        sred[t] = f * Wout[t];
    }
    __syncthreads();
    if (t < 64) {
        float v = sred[t] + sred[t + 64];
#pragma unroll
        for (int off = 32; off > 0; off >>= 1) v += __shfl_down(v, off);
        if (t == 0) {
            float logit = v + bout[0];
            out[gr] = 1.0f / (1.0f + expf(-logit));
            out[NUM_GRAPHS + gr] = logit;
        }
    }
}

extern "C" void kernel_launch(void* const* d_in, const int* in_sizes, int n_in,
                              void* d_out, int out_size, void* d_ws, size_t ws_size,
                              hipStream_t stream) {
    const int* tok   = (const int*)d_in[0];
    const int* eidx  = (const int*)d_in[1];
    const int* batch = (const int*)d_in[2];
    const float* emb = (const float*)d_in[3];
    const float* Wp  = (const float*)d_in[4];
    const float* bp  = (const float*)d_in[5];
    const float* W1  = (const float*)d_in[6];
    const float* b1  = (const float*)d_in[7];
    const float* W2  = (const float*)d_in[8];
    const float* b2  = (const float*)d_in[9];
    const float* Wfc = (const float*)d_in[10];
    const float* bfc = (const float*)d_in[11];
    const float* Wout= (const float*)d_in[12];
    const float* bout= (const float*)d_in[13];
    float* out = (float*)d_out;

    const int N = in_sizes[2];
    const int E = in_sizes[1] / 2;
    const int* src = eidx;
    const int* dst = eidx + E;
    const int Np = (N + 3) & ~3;
    const int nbuck = (N + 255) / 256;               // 391 for N=100k
    const int nchunk = (E + CHUNK - 1) / CHUNK;      // 196
    const int emb_n4 = in_sizes[3] / 4;              // float4 count of emb

    // workspace layout (float units)
    float* ws = (float*)d_ws;
    size_t off = 0;
    float* dis     = ws + off;            off += Np;
    __half* mean16 = (__half*)(ws + off); off += (size_t)Np * 32;
    __half* agg16  = (__half*)(ws + off); off += (size_t)Np * 32;  // unused (layout stability)
    float* rowsum  = ws + off;            off += Np;
    __half* h2buf  = (__half*)(ws + off); off += (size_t)Np * 64;
    __half* xfin16 = (__half*)(ws + off); off += (size_t)Np * 64;
    __half* emb16  = (__half*)(ws + off); off += (size_t)(in_sizes[3] / 2 + 4);
    _Float16* Wf16t = (_Float16*)(ws + off); off += 4096;
    _Float16* W2t   = (_Float16*)(ws + off); off += 8192;
    float* bf      = ws + off;            off += 128;
    int* row_start = (int*)(ws + off);    off += Np + 4;
    int* staged    = (int*)(ws + off);    off += E;
    int* total     = (int*)(ws + off);    off += NBUCK_MAX;
    int* bucket_base   = (int*)(ws + off); off += NBUCK_MAX + 8;
    int2* csr      = (int2*)(ws + off);   // E int2
    // hist2d / chunkbase alias h2buf: only live during the sort pipeline, h2buf is
    // first written by agg64_dense_kernel which runs strictly after csr_write.
    int* hist2d    = (int*)h2buf;                        // [nchunk][NBUCK_MAX]
    int* chunkbase = hist2d + (size_t)nchunk * NBUCK_MAX;  // [nchunk][NBUCK_MAX]

    // --- fused weight prep + emb fp16 conversion (one launch) ---
    prep_fused_kernel<<<128 + (emb_n4 + 255) / 256, 256, 0, stream>>>(
        Wp, W1, W2, bp, emb, Wf16t, W2t, bf, emb16, emb_n4);

    // --- combined: bucket hist + embed/token-mean (one launch) ---
    hist_embed_kernel<<<nchunk + (N + 7) / 8, 512, 0, stream>>>(
        dst, hist2d, E, nbuck, nchunk, tok, emb16, mean16, N);

    // --- per-bucket chunk scan -> chunkbase, total ---
    chunk_scan_kernel<<<nbuck, 64, 0, stream>>>(hist2d, chunkbase, total, nchunk);

    // --- one-pass scatter (derives bucket_base in-LDS; block 0 publishes it) ---
    binscatter_kernel<<<nchunk, 512, 0, stream>>>(src, dst, total, chunkbase,
                                                  bucket_base, staged, E, nbuck);

    bucket_count_kernel<<<nbuck, 256, 0, stream>>>(staged, bucket_base, row_start, dis, N, E);
    csr_write_kernel<<<nbuck, 256, 0, stream>>>(staged, bucket_base, row_start, dis,
                                                csr, rowsum, N);

    // --- fused: 64-dim aggregate (8 thr/node, launch_bounds 4) + MFMA dense chain -> h2buf ---
    agg64_dense_kernel<<<(N + NB - 1) / NB, 256, 0, stream>>>(mean16, row_start, csr, dis,
                                                              rowsum, Wf16t, bf, b1, W2t,
                                                              h2buf, N);

    // --- layer 2 aggregate (fp16 packed, 1 wave/node, wide tail) + b2 + ReLU -> xfin16 ---
    gcn_agg128_kernel<<<(N + 3) / 4, 256, 0, stream>>>(h2buf, row_start, csr, dis, b2,
                                                       xfin16, N);

    // --- fused global mean pool + head ---
    pool_head_kernel<<<NUM_GRAPHS, 256, 0, stream>>>(xfin16, batch, Wfc, bfc, Wout, bout,
                                                     out, N);
}

// Round 11
// 304.576 us; speedup vs baseline: 1.1812x; 1.0122x over previous
//
#include <hip/hip_runtime.h>
#include <hip/hip_bf16.h>
#include <hip/hip_fp16.h>
#include <math.h>

#define N_TOKENS 16
#define TOK_DIM 64
#define NODE_DIM 64
#define HID 128
#define FC 128
#define NUM_GRAPHS 1024
#define NBUCK_MAX 512
#define CHUNK 8192

typedef _Float16 f16x8 __attribute__((ext_vector_type(8)));
typedef float f32x4 __attribute__((ext_vector_type(4)));

__device__ __forceinline__ __half2 shfl_xor_h2(__half2 v, int mask) {
    int i = *(int*)&v;
    i = __shfl_xor(i, mask);
    return *(__half2*)&i;
}

// ---------------- fused prep: weights (blocks 0..127) + emb fp32->fp16 (rest) ----------------
__global__ void prep_fused_kernel(const float* __restrict__ Wp, const float* __restrict__ W1,
                                  const float* __restrict__ W2, const float* __restrict__ bp,
                                  const float* __restrict__ emb,
                                  _Float16* __restrict__ Wf16t, _Float16* __restrict__ W2t,
                                  float* __restrict__ bf, __half* __restrict__ emb16, int n4) {
    int b = blockIdx.x;
    int t = threadIdx.x;
    if (b < 128) {
        int n = b;
        if (t < 64) {
            float acc = 0.f;
#pragma unroll
            for (int d = 0; d < 64; d++) acc += Wp[t * 64 + d] * W1[d * 128 + n];
            Wf16t[(size_t)n * 64 + t] = (_Float16)acc;
        } else if (t < 128) {
            int d = t - 64;  // lane of wave 1
            float v = bp[d] * W1[d * 128 + n];
#pragma unroll
            for (int off = 32; off > 0; off >>= 1) v += __shfl_down(v, off);
            if (d == 0) bf[n] = v;
        }
        if (t < 128) W2t[(size_t)n * 128 + t] = (_Float16)W2[(size_t)t * 128 + n];
    } else {
        int i = (b - 128) * 256 + t;
        if (i < n4) {
            float4 v = ((const float4*)emb)[i];
            __half2 h0 = __floats2half2_rn(v.x, v.y);
            __half2 h1 = __floats2half2_rn(v.z, v.w);
            float2 p;
            ((__half2*)&p)[0] = h0;
            ((__half2*)&p)[1] = h1;
            ((float2*)emb16)[i] = p;
        }
    }
}

// ---------------- combined: bucket hist (blocks 0..nchunk-1) + embed/token-mean (rest) ----------------
// hist: per-chunk per-bucket counts -> hist2d[chunk][bucket]
// embed: 512 thr = 8 nodes/block; lane (q,l): q=j>>3 token slot, l=j&7 feature float4
__global__ void hist_embed_kernel(const int* __restrict__ dst, int* __restrict__ hist2d,
                                  int E, int nbuck, int nchunk,
                                  const int* __restrict__ tok,
                                  const __half* __restrict__ emb16,
                                  __half* __restrict__ mean16, int N) {
    int b = blockIdx.x;
    int t = threadIdx.x;
    if (b < nchunk) {
        __shared__ int h[NBUCK_MAX];
        for (int i = t; i < nbuck; i += 512) h[i] = 0;
        __syncthreads();
        int base = b * CHUNK;
        for (int i = t; i < CHUNK; i += 512) {
            int e = base + i;
            if (e < E) atomicAdd(&h[dst[e] >> 8], 1);
        }
        __syncthreads();
        int* row = hist2d + (size_t)b * NBUCK_MAX;
        for (int i = t; i < nbuck; i += 512) row[i] = h[i];
    } else {
        int w = t >> 6, j = t & 63;
        int q = j >> 3, l = j & 7;
        int i = (b - nchunk) * 8 + w;
        if (i >= N) return;
        const float4* e4 = (const float4*)emb16;  // row = 8 float4 (64 halfs)
        int t0 = tok[i * 16 + q];
        int t1 = tok[i * 16 + q + 8];
        float4 v0 = e4[(size_t)t0 * 8 + l];
        float4 v1 = e4[(size_t)t1 * 8 + l];
        const __half2* p0 = (const __half2*)&v0;
        const __half2* p1 = (const __half2*)&v1;
        __half2 a0 = __hadd2(p0[0], p1[0]);
        __half2 a1 = __hadd2(p0[1], p1[1]);
        __half2 a2 = __hadd2(p0[2], p1[2]);
        __half2 a3 = __hadd2(p0[3], p1[3]);
#pragma unroll
        for (int mask = 8; mask <= 32; mask <<= 1) {
            a0 = __hadd2(a0, shfl_xor_h2(a0, mask));
            a1 = __hadd2(a1, shfl_xor_h2(a1, mask));
            a2 = __hadd2(a2, shfl_xor_h2(a2, mask));
            a3 = __hadd2(a3, shfl_xor_h2(a3, mask));
        }
        if (q == 0) {
            __half2 inv = __floats2half2_rn(1.0f / 16.0f, 1.0f / 16.0f);
            float4 packed;
            __half2* pp = (__half2*)&packed;
            pp[0] = __hmul2(a0, inv);
            pp[1] = __hmul2(a1, inv);
            pp[2] = __hmul2(a2, inv);
            pp[3] = __hmul2(a3, inv);
            ((float4*)mean16)[(size_t)i * 8 + l] = packed;
        }
    }
}

// per-bucket exclusive scan over chunks -> chunkbase[chunk][bucket], total[bucket]
// grid = nbuck blocks x 64 threads (one wave each)
__global__ void chunk_scan_kernel(const int* __restrict__ hist2d, int* __restrict__ chunkbase,
                                  int* __restrict__ total, int nchunk) {
    int b = blockIdx.x;
    int lane = threadIdx.x;  // 0..63
    int run = 0;
    for (int c0 = 0; c0 < nchunk; c0 += 64) {
        int c = c0 + lane;
        int v = (c < nchunk) ? hist2d[(size_t)c * NBUCK_MAX + b] : 0;
        int s = v;
#pragma unroll
        for (int off = 1; off < 64; off <<= 1) {
            int u = __shfl_up(s, off);
            if (lane >= off) s += u;
        }
        if (c < nchunk) chunkbase[(size_t)c * NBUCK_MAX + b] = s - v + run;
        run += __shfl(s, 63);
    }
    if (lane == 0) total[b] = run;
}

// one-pass scatter; each block re-derives bucket_base from total[] via LDS scan
// (block 0 publishes bucket_base for downstream kernels). packed val = src | (dst&255)<<17
__global__ void binscatter_kernel(const int* __restrict__ src, const int* __restrict__ dst,
                                  const int* __restrict__ total,
                                  const int* __restrict__ chunkbase,
                                  int* __restrict__ bucket_base,
                                  int* __restrict__ staged, int E, int nbuck) {
    __shared__ int s[512];
    __shared__ int h[NBUCK_MAX];
    int t = threadIdx.x;
    int v = (t < nbuck) ? total[t] : 0;
    s[t] = v;
    __syncthreads();
    for (int off = 1; off < 512; off <<= 1) {
        int add = (t >= off) ? s[t - off] : 0;
        __syncthreads();
        s[t] += add;
        __syncthreads();
    }
    const int* cb = chunkbase + (size_t)blockIdx.x * NBUCK_MAX;
    if (t < nbuck) h[t] = (s[t] - v) + cb[t];
    if (blockIdx.x == 0) {
        if (t < nbuck) bucket_base[t] = s[t] - v;
        if (t == 511) bucket_base[nbuck] = s[511];
    }
    __syncthreads();
    int base = blockIdx.x * CHUNK;
    for (int i = t; i < CHUNK; i += 512) {
        int e = base + i;
        if (e < E) {
            int d = dst[e], sv = src[e];
            int b = d >> 8;
            int r = atomicAdd(&h[b], 1);
            staged[r] = sv | ((d & 255) << 17);
        }
    }
}

// per bucket: per-node degree -> row_start + dis (coalesced writes)
__global__ void bucket_count_kernel(const int* __restrict__ staged,
                                    const int* __restrict__ bucket_base,
                                    int* __restrict__ row_start, float* __restrict__ dis,
                                    int N, int E) {
    __shared__ int cnt[256];
    __shared__ int sc[256];
    int b = blockIdx.x;
    int t = threadIdx.x;
    cnt[t] = 0;
    __syncthreads();
    int rb0 = bucket_base[b], rb1 = bucket_base[b + 1];
    for (int i = rb0 + t; i < rb1; i += 256) atomicAdd(&cnt[staged[i] >> 17], 1);
    __syncthreads();
    int v = cnt[t];
    sc[t] = v;
    __syncthreads();
    for (int off = 1; off < 256; off <<= 1) {
        int add = (t >= off) ? sc[t - off] : 0;
        __syncthreads();
        sc[t] += add;
        __syncthreads();
    }
    int node = b * 256 + t;
    if (node < N) {
        row_start[node] = rb0 + sc[t] - v;  // exclusive
        dis[node] = rsqrtf(1.0f + (float)v);  // +1 self loop
    }
    if (b == 0 && t == 0) row_start[N] = E;
}

// per bucket: final CSR (src, half2(w,w)) + rowsum — block-local contiguous region
__global__ void csr_write_kernel(const int* __restrict__ staged,
                                 const int* __restrict__ bucket_base,
                                 const int* __restrict__ row_start,
                                 const float* __restrict__ dis,
                                 int2* __restrict__ csr, float* __restrict__ rowsum, int N) {
    __shared__ int cur[256];
    __shared__ float dl[256];
    __shared__ float wsum[256];
    int b = blockIdx.x;
    int t = threadIdx.x;
    int node = b * 256 + t;
    cur[t] = (node < N) ? row_start[node] : 0;
    dl[t] = (node < N) ? dis[node] : 0.f;
    wsum[t] = 0.f;
    __syncthreads();
    int rb0 = bucket_base[b], rb1 = bucket_base[b + 1];
    for (int i = rb0 + t; i < rb1; i += 256) {
        int v = staged[i];
        int s = v & 131071;
        int dloc = v >> 17;
        float w = dis[s] * dl[dloc];
        int pos = atomicAdd(&cur[dloc], 1);
        __half2 wh = __floats2half2_rn(w, w);
        csr[pos] = make_int2(s, *(int*)&wh);
        atomicAdd(&wsum[dloc], w);
    }
    __syncthreads();
    if (node < N) rowsum[node] = wsum[t] + dl[t] * dl[t];
}

// ---------------- fused agg64 + MFMA dense chain (r8 config — best measured) ----------------
// block = 32 nodes, 4 waves. Phase 1: 8 threads per node (nl=t>>3, l=t&7 feature float4),
// all 32 nodes' gather chains concurrent. Phase 2: dense chain via MFMA.
// launch_bounds(256,6): r10 proved the allocator ignores extra VGPR headroom (36 vs 32,
// flat perf, lost occupancy) — keep the measured-best bound.
#define NB 32
__global__ __launch_bounds__(256, 6)
void agg64_dense_kernel(const __half* __restrict__ mean16,
                        const int* __restrict__ row_start,
                        const int2* __restrict__ csr,
                        const float* __restrict__ dis,
                        const float* __restrict__ rowsum,
                        const _Float16* __restrict__ Wf16t,  // [128][64]
                        const float* __restrict__ bf,
                        const float* __restrict__ b1,
                        const _Float16* __restrict__ W2t,    // [128][128]
                        __half* __restrict__ h2, int N) {
    __shared__ _Float16 sagg[32][72];
    __shared__ _Float16 sx1[32][136];
    __shared__ float srs[32];
    int t = threadIdx.x;
    int nb0 = blockIdx.x * NB;
    const float4* m4 = (const float4*)mean16;  // row = 8 float4 (64 halfs)

    if (t < 32) srs[t] = (nb0 + t < N) ? rowsum[nb0 + t] : 0.f;

    // ---- phase 1: gather, 8 threads per node, 32 nodes in parallel ----
    {
        int nl = t >> 3;   // node_local 0..31
        int l = t & 7;     // feature float4 block 0..7
        int node = nb0 + nl;
        __half2 a0, a1, a2, a3;
        a0 = a1 = a2 = a3 = __floats2half2_rn(0.f, 0.f);
        if (node < N) {
            int beg = row_start[node];
            int end = row_start[node + 1];
            float d = dis[node];
            {
                float4 raw = m4[(size_t)node * 8 + l];
                const __half2* hp = (const __half2*)&raw;
                float d2f = d * d;
                __half2 d2h = __floats2half2_rn(d2f, d2f);
                a0 = __hmul2(hp[0], d2h); a1 = __hmul2(hp[1], d2h);
                a2 = __hmul2(hp[2], d2h); a3 = __hmul2(hp[3], d2h);
            }
            int k = beg;
            int kfull = beg + ((end - beg) & ~7);
            for (; k < kfull; k += 8) {  // unguarded: 8 edges, all in flight
                int2 e[8];
                float4 v[8];
#pragma unroll
                for (int m = 0; m < 8; m++) e[m] = csr[k + m];
#pragma unroll
                for (int m = 0; m < 8; m++) v[m] = m4[(size_t)e[m].x * 8 + l];
#pragma unroll
                for (int m = 0; m < 8; m++) {
                    __half2 wh = *(__half2*)&e[m].y;
                    const __half2* hp = (const __half2*)&v[m];
                    a0 = __hfma2(hp[0], wh, a0);
                    a1 = __hfma2(hp[1], wh, a1);
                    a2 = __hfma2(hp[2], wh, a2);
                    a3 = __hfma2(hp[3], wh, a3);
                }
            }
            if (k < end) {  // single guarded round of 8
                int2 e[8];
                float4 v[8];
#pragma unroll
                for (int m = 0; m < 8; m++) {
                    int kk = k + m;
                    e[m] = (kk < end) ? csr[kk] : make_int2(0, 0);  // wh=0 => no-op
                }
#pragma unroll
                for (int m = 0; m < 8; m++) v[m] = m4[(size_t)e[m].x * 8 + l];
#pragma unroll
                for (int m = 0; m < 8; m++) {
                    __half2 wh = *(__half2*)&e[m].y;
                    const __half2* hp = (const __half2*)&v[m];
                    a0 = __hfma2(hp[0], wh, a0);
                    a1 = __hfma2(hp[1], wh, a1);
                    a2 = __hfma2(hp[2], wh, a2);
                    a3 = __hfma2(hp[3], wh, a3);
                }
            }
        }
        float4 packed;
        __half2* pp = (__half2*)&packed;
        pp[0] = a0; pp[1] = a1; pp[2] = a2; pp[3] = a3;
        *(float4*)(&sagg[nl][l * 8]) = packed;
    }
    __syncthreads();

    // ---- phase 2: MFMA dense chain ----
    int wv = t >> 6, lane = t & 63;
    int rh = wv & 1;
    int ncb = (wv >> 1) * 64;
    int m16 = lane & 15;
    int qq = lane >> 4;

    f32x4 c0 = {}, c1 = {}, c2 = {}, c3 = {};
#pragma unroll
    for (int ks = 0; ks < 2; ks++) {
        int k0 = ks * 32 + qq * 8;
        f16x8 afrag = *(const f16x8*)(&sagg[rh * 16 + m16][k0]);
        f16x8 b0 = *(const f16x8*)(Wf16t + (size_t)(ncb + 0 * 16 + m16) * 64 + k0);
        f16x8 b1f = *(const f16x8*)(Wf16t + (size_t)(ncb + 1 * 16 + m16) * 64 + k0);
        f16x8 b2f = *(const f16x8*)(Wf16t + (size_t)(ncb + 2 * 16 + m16) * 64 + k0);
        f16x8 b3f = *(const f16x8*)(Wf16t + (size_t)(ncb + 3 * 16 + m16) * 64 + k0);
        c0 = __builtin_amdgcn_mfma_f32_16x16x32_f16(afrag, b0, c0, 0, 0, 0);
        c1 = __builtin_amdgcn_mfma_f32_16x16x32_f16(afrag, b1f, c1, 0, 0, 0);
        c2 = __builtin_amdgcn_mfma_f32_16x16x32_f16(afrag, b2f, c2, 0, 0, 0);
        c3 = __builtin_amdgcn_mfma_f32_16x16x32_f16(afrag, b3f, c3, 0, 0, 0);
    }
    {
        f32x4 cc[4] = {c0, c1, c2, c3};
#pragma unroll
        for (int nt = 0; nt < 4; nt++) {
            int ncol = ncb + nt * 16 + m16;
            float bfj = bf[ncol], b1j = b1[ncol];
#pragma unroll
            for (int r = 0; r < 4; r++) {
                int mrow = qq * 4 + r;
                float z = cc[nt][r] + srs[rh * 16 + mrow] * bfj + b1j;
                sx1[rh * 16 + mrow][ncol] = (_Float16)fmaxf(z, 0.f);
            }
        }
    }
    __syncthreads();

    f32x4 d0 = {}, d1 = {}, d2 = {}, d3 = {};
#pragma unroll
    for (int ks = 0; ks < 4; ks++) {
        int k0 = ks * 32 + qq * 8;
        f16x8 afrag = *(const f16x8*)(&sx1[rh * 16 + m16][k0]);
        f16x8 b0 = *(const f16x8*)(W2t + (size_t)(ncb + 0 * 16 + m16) * 128 + k0);
        f16x8 b1f = *(const f16x8*)(W2t + (size_t)(ncb + 1 * 16 + m16) * 128 + k0);
        f16x8 b2f = *(const f16x8*)(W2t + (size_t)(ncb + 2 * 16 + m16) * 128 + k0);
        f16x8 b3f = *(const f16x8*)(W2t + (size_t)(ncb + 3 * 16 + m16) * 128 + k0);
        d0 = __builtin_amdgcn_mfma_f32_16x16x32_f16(afrag, b0, d0, 0, 0, 0);
        d1 = __builtin_amdgcn_mfma_f32_16x16x32_f16(afrag, b1f, d1, 0, 0, 0);
        d2 = __builtin_amdgcn_mfma_f32_16x16x32_f16(afrag, b2f, d2, 0, 0, 0);
        d3 = __builtin_amdgcn_mfma_f32_16x16x32_f16(afrag, b3f, d3, 0, 0, 0);
    }
    {
        f32x4 dd[4] = {d0, d1, d2, d3};
#pragma unroll
        for (int nt = 0; nt < 4; nt++) {
            int ncol = ncb + nt * 16 + m16;
#pragma unroll
            for (int r = 0; r < 4; r++) {
                int node = nb0 + rh * 16 + qq * 4 + r;
                if (node < N) h2[(size_t)node * 128 + ncol] = __float2half(dd[nt][r]);
            }
        }
    }
}

// ---------------- layer 2: agg128 fp16 packed accumulate, 1 wave/node, 4 rows per gather ----------------
// lane (q,l): q=j>>4 edge slot (4), l=j&15 feature block (float4 = 4 half2)
__global__ __launch_bounds__(256, 8)
void gcn_agg128_kernel(const __half* __restrict__ hsrc,
                       const int* __restrict__ row_start,
                       const int2* __restrict__ csr,
                       const float* __restrict__ dis,
                       const float* __restrict__ b2,
                       __half* __restrict__ outx, int N) {
    int t = threadIdx.x;
    int w = t >> 6, j = t & 63;
    int q = j >> 4, l = j & 15;
    int node = blockIdx.x * 4 + w;
    if (node >= N) return;
    const float4* h4 = (const float4*)hsrc;  // row = 16 float4 (128 halfs)
    int beg = row_start[node];
    int end = row_start[node + 1];
    float d = dis[node];
    __half2 a0, a1, a2, a3;
    {
        float4 raw = h4[(size_t)node * 16 + l];
        const __half2* hp = (const __half2*)&raw;
        float d2f = d * d * ((q == 0) ? 1.f : 0.f);
        __half2 d2h = __floats2half2_rn(d2f, d2f);
        a0 = __hmul2(hp[0], d2h); a1 = __hmul2(hp[1], d2h);
        a2 = __hmul2(hp[2], d2h); a3 = __hmul2(hp[3], d2h);
    }
    int k = beg;
    int kfull = beg + ((end - beg) & ~31);
    for (; k < kfull; k += 32) {  // unguarded: 8 batches x 4 slots
        int2 e[8];
        float4 v[8];
#pragma unroll
        for (int m = 0; m < 8; m++) e[m] = csr[k + 4 * m + q];
#pragma unroll
        for (int m = 0; m < 8; m++) v[m] = h4[(size_t)e[m].x * 16 + l];
#pragma unroll
        for (int m = 0; m < 8; m++) {
            __half2 wh = *(__half2*)&e[m].y;
            const __half2* hp = (const __half2*)&v[m];
            a0 = __hfma2(hp[0], wh, a0);
            a1 = __hfma2(hp[1], wh, a1);
            a2 = __hfma2(hp[2], wh, a2);
            a3 = __hfma2(hp[3], wh, a3);
        }
    }
    if (k < end) {  // single guarded round: 8 batches x 4 slots = 32 edges
        int2 e[8];
        float4 v[8];
#pragma unroll
        for (int m = 0; m < 8; m++) {
            int kk = k + 4 * m + q;
            e[m] = (kk < end) ? csr[kk] : make_int2(0, 0);  // wh=0 => no-op
        }
#pragma unroll
        for (int m = 0; m < 8; m++) v[m] = h4[(size_t)e[m].x * 16 + l];
#pragma unroll
        for (int m = 0; m < 8; m++) {
            __half2 wh = *(__half2*)&e[m].y;
            const __half2* hp = (const __half2*)&v[m];
            a0 = __hfma2(hp[0], wh, a0);
            a1 = __hfma2(hp[1], wh, a1);
            a2 = __hfma2(hp[2], wh, a2);
            a3 = __hfma2(hp[3], wh, a3);
        }
    }
    // fold across q (lane bits 4,5)
#pragma unroll
    for (int mask = 16; mask <= 32; mask <<= 1) {
        a0 = __hadd2(a0, shfl_xor_h2(a0, mask));
        a1 = __hadd2(a1, shfl_xor_h2(a1, mask));
        a2 = __hadd2(a2, shfl_xor_h2(a2, mask));
        a3 = __hadd2(a3, shfl_xor_h2(a3, mask));
    }
    if (q == 0) {
        // fp32 epilogue: + b2, relu, pack fp16
        float2 f0 = __half22float2(a0), f1 = __half22float2(a1);
        float2 f2 = __half22float2(a2), f3 = __half22float2(a3);
        const float4* b4 = (const float4*)b2;
        float4 ba = b4[l * 2], bb = b4[l * 2 + 1];
        __half2 o0 = __floats2half2_rn(fmaxf(f0.x + ba.x, 0.f), fmaxf(f0.y + ba.y, 0.f));
        __half2 o1 = __floats2half2_rn(fmaxf(f1.x + ba.z, 0.f), fmaxf(f1.y + ba.w, 0.f));
        __half2 o2 = __floats2half2_rn(fmaxf(f2.x + bb.x, 0.f), fmaxf(f2.y + bb.y, 0.f));
        __half2 o3 = __floats2half2_rn(fmaxf(f3.x + bb.z, 0.f), fmaxf(f3.y + bb.w, 0.f));
        float4 packed;
        __half2* pp = (__half2*)&packed;
        pp[0] = o0; pp[1] = o1; pp[2] = o2; pp[3] = o3;
        ((float4*)outx)[(size_t)node * 16 + l] = packed;
    }
}

// ---------------- fused pool + head: one block (256 threads, 4 row-waves) per graph ----------------
__device__ __forceinline__ int lower_bound_i(const int* __restrict__ a, int n, int val) {
    int lo = 0, hi = n;
    while (lo < hi) {
        int mid = (lo + hi) >> 1;
        if (a[mid] < val) lo = mid + 1; else hi = mid;
    }
    return lo;
}

__global__ void pool_head_kernel(const __half* __restrict__ x,
                                 const int* __restrict__ batch,
                                 const float* __restrict__ Wfc,
                                 const float* __restrict__ bfc,
                                 const float* __restrict__ Wout,
                                 const float* __restrict__ bout,
                                 float* __restrict__ out, int N) {
    int gr = blockIdx.x;
    int t = threadIdx.x;  // 0..255
    int j2 = t & 63, w = t >> 6;  // 4 row-waves
    __shared__ float2 spart[4][64];
    __shared__ float sg[128];
    __shared__ float sfc[2][128];
    __shared__ float sred[128];
    int beg = lower_bound_i(batch, N, gr);
    int end = lower_bound_i(batch, N, gr + 1);
    const __half2* x2 = (const __half2*)x;  // row stride 64 half2
    float2 acc = make_float2(0.f, 0.f);
    for (int i = beg + w; i < end; i += 4) {
        float2 a = __half22float2(x2[(size_t)i * 64 + j2]);
        acc.x += a.x; acc.y += a.y;
    }
    spart[w][j2] = acc;
    __syncthreads();
    if (t < 64) {
        float inv = 1.0f / fmaxf((float)(end - beg), 1.0f);
        float2 s0 = spart[0][t], s1 = spart[1][t];
        float2 s2 = spart[2][t], s3 = spart[3][t];
        sg[2 * t] = (s0.x + s1.x + s2.x + s3.x) * inv;
        sg[2 * t + 1] = (s0.y + s1.y + s2.y + s3.y) * inv;
    }
    __syncthreads();
    // FC: 256 threads, output j = t&127, k-half = t>>7
    int j = t & 127, hb = t >> 7;
    float a = 0.f;
#pragma unroll
    for (int k = 0; k < 64; k++) a += sg[hb * 64 + k] * Wfc[(hb * 64 + k) * 128 + j];
    sfc[hb][j] = a;
    __syncthreads();
    if (t < 128) {
        float aa = sfc[0][t] + sfc[1][t] + bfc[t];
        float f = fmaxf(aa, 0.f);
        sred[t] = f * Wout[t];
    }
    __syncthreads();
    if (t < 64) {
        float v = sred[t] + sred[t + 64];
#pragma unroll
        for (int off = 32; off > 0; off >>= 1) v += __shfl_down(v, off);
        if (t == 0) {
            float logit = v + bout[0];
            out[gr] = 1.0f / (1.0f + expf(-logit));
            out[NUM_GRAPHS + gr] = logit;
        }
    }
}

extern "C" void kernel_launch(void* const* d_in, const int* in_sizes, int n_in,
                              void* d_out, int out_size, void* d_ws, size_t ws_size,
                              hipStream_t stream) {
    const int* tok   = (const int*)d_in[0];
    const int* eidx  = (const int*)d_in[1];
    const int* batch = (const int*)d_in[2];
    const float* emb = (const float*)d_in[3];
    const float* Wp  = (const float*)d_in[4];
    const float* bp  = (const float*)d_in[5];
    const float* W1  = (const float*)d_in[6];
    const float* b1  = (const float*)d_in[7];
    const float* W2  = (const float*)d_in[8];
    const float* b2  = (const float*)d_in[9];
    const float* Wfc = (const float*)d_in[10];
    const float* bfc = (const float*)d_in[11];
    const float* Wout= (const float*)d_in[12];
    const float* bout= (const float*)d_in[13];
    float* out = (float*)d_out;

    const int N = in_sizes[2];
    const int E = in_sizes[1] / 2;
    const int* src = eidx;
    const int* dst = eidx + E;
    const int Np = (N + 3) & ~3;
    const int nbuck = (N + 255) / 256;               // 391 for N=100k
    const int nchunk = (E + CHUNK - 1) / CHUNK;      // 196
    const int emb_n4 = in_sizes[3] / 4;              // float4 count of emb

    // workspace layout (float units)
    float* ws = (float*)d_ws;
    size_t off = 0;
    float* dis     = ws + off;            off += Np;
    __half* mean16 = (__half*)(ws + off); off += (size_t)Np * 32;
    __half* agg16  = (__half*)(ws + off); off += (size_t)Np * 32;  // unused (layout stability)
    float* rowsum  = ws + off;            off += Np;
    __half* h2buf  = (__half*)(ws + off); off += (size_t)Np * 64;
    __half* xfin16 = (__half*)(ws + off); off += (size_t)Np * 64;
    __half* emb16  = (__half*)(ws + off); off += (size_t)(in_sizes[3] / 2 + 4);
    _Float16* Wf16t = (_Float16*)(ws + off); off += 4096;
    _Float16* W2t   = (_Float16*)(ws + off); off += 8192;
    float* bf      = ws + off;            off += 128;
    int* row_start = (int*)(ws + off);    off += Np + 4;
    int* staged    = (int*)(ws + off);    off += E;
    int* total     = (int*)(ws + off);    off += NBUCK_MAX;
    int* bucket_base   = (int*)(ws + off); off += NBUCK_MAX + 8;
    int2* csr      = (int2*)(ws + off);   // E int2
    // hist2d / chunkbase alias h2buf: only live during the sort pipeline, h2buf is
    // first written by agg64_dense_kernel which runs strictly after csr_write.
    int* hist2d    = (int*)h2buf;                        // [nchunk][NBUCK_MAX]
    int* chunkbase = hist2d + (size_t)nchunk * NBUCK_MAX;  // [nchunk][NBUCK_MAX]

    // --- fused weight prep + emb fp16 conversion (one launch) ---
    prep_fused_kernel<<<128 + (emb_n4 + 255) / 256, 256, 0, stream>>>(
        Wp, W1, W2, bp, emb, Wf16t, W2t, bf, emb16, emb_n4);

    // --- combined: bucket hist + embed/token-mean (one launch) ---
    hist_embed_kernel<<<nchunk + (N + 7) / 8, 512, 0, stream>>>(
        dst, hist2d, E, nbuck, nchunk, tok, emb16, mean16, N);

    // --- per-bucket chunk scan -> chunkbase, total ---
    chunk_scan_kernel<<<nbuck, 64, 0, stream>>>(hist2d, chunkbase, total, nchunk);

    // --- one-pass scatter (derives bucket_base in-LDS; block 0 publishes it) ---
    binscatter_kernel<<<nchunk, 512, 0, stream>>>(src, dst, total, chunkbase,
                                                  bucket_base, staged, E, nbuck);

    bucket_count_kernel<<<nbuck, 256, 0, stream>>>(staged, bucket_base, row_start, dis, N, E);
    csr_write_kernel<<<nbuck, 256, 0, stream>>>(staged, bucket_base, row_start, dis,
                                                csr, rowsum, N);

    // --- fused: 64-dim aggregate (8 thr/node) + MFMA dense chain -> h2buf ---
    agg64_dense_kernel<<<(N + NB - 1) / NB, 256, 0, stream>>>(mean16, row_start, csr, dis,
                                                              rowsum, Wf16t, bf, b1, W2t,
                                                              h2buf, N);

    // --- layer 2 aggregate (fp16 packed, 1 wave/node, wide tail) + b2 + ReLU -> xfin16 ---
    gcn_agg128_kernel<<<(N + 3) / 4, 256, 0, stream>>>(h2buf, row_start, csr, dis, b2,
                                                       xfin16, N);

    // --- fused global mean pool + head ---
    pool_head_kernel<<<NUM_GRAPHS, 256, 0, stream>>>(xfin16, batch, Wfc, bfc, Wout, bout,
                                                     out, N);
}

// Round 12
// 294.382 us; speedup vs baseline: 1.2221x; 1.0346x over previous
//
#include <hip/hip_runtime.h>
#include <hip/hip_bf16.h>
#include <hip/hip_fp16.h>
#include <math.h>

#define N_TOKENS 16
#define TOK_DIM 64
#define NODE_DIM 64
#define HID 128
#define FC 128
#define NUM_GRAPHS 1024
#define NBUCK_MAX 512
#define CHUNK 8192

typedef _Float16 f16x8 __attribute__((ext_vector_type(8)));
typedef float f32x4 __attribute__((ext_vector_type(4)));

__device__ __forceinline__ __half2 shfl_xor_h2(__half2 v, int mask) {
    int i = *(int*)&v;
    i = __shfl_xor(i, mask);
    return *(__half2*)&i;
}

// unpack weightless-CSR entry: low 17 bits = src, high 15 bits = fp16(dis[src]) sans sign
__device__ __forceinline__ void unpack_csr(unsigned e, unsigned& s, __half2& wh) {
    s = e & 131071u;
    __half hd = __ushort_as_half((unsigned short)(e >> 17));
    wh = __halves2half2(hd, hd);
}

// ---------------- fused prep: weights (blocks 0..127) + emb fp32->fp16 (rest) ----------------
__global__ void prep_fused_kernel(const float* __restrict__ Wp, const float* __restrict__ W1,
                                  const float* __restrict__ W2, const float* __restrict__ bp,
                                  const float* __restrict__ emb,
                                  _Float16* __restrict__ Wf16t, _Float16* __restrict__ W2t,
                                  float* __restrict__ bf, __half* __restrict__ emb16, int n4) {
    int b = blockIdx.x;
    int t = threadIdx.x;
    if (b < 128) {
        int n = b;
        if (t < 64) {
            float acc = 0.f;
#pragma unroll
            for (int d = 0; d < 64; d++) acc += Wp[t * 64 + d] * W1[d * 128 + n];
            Wf16t[(size_t)n * 64 + t] = (_Float16)acc;
        } else if (t < 128) {
            int d = t - 64;  // lane of wave 1
            float v = bp[d] * W1[d * 128 + n];
#pragma unroll
            for (int off = 32; off > 0; off >>= 1) v += __shfl_down(v, off);
            if (d == 0) bf[n] = v;
        }
        if (t < 128) W2t[(size_t)n * 128 + t] = (_Float16)W2[(size_t)t * 128 + n];
    } else {
        int i = (b - 128) * 256 + t;
        if (i < n4) {
            float4 v = ((const float4*)emb)[i];
            __half2 h0 = __floats2half2_rn(v.x, v.y);
            __half2 h1 = __floats2half2_rn(v.z, v.w);
            float2 p;
            ((__half2*)&p)[0] = h0;
            ((__half2*)&p)[1] = h1;
            ((float2*)emb16)[i] = p;
        }
    }
}

// ---------------- combined: bucket hist (blocks 0..nchunk-1) + embed/token-mean (rest) ----------------
__global__ void hist_embed_kernel(const int* __restrict__ dst, int* __restrict__ hist2d,
                                  int E, int nbuck, int nchunk,
                                  const int* __restrict__ tok,
                                  const __half* __restrict__ emb16,
                                  __half* __restrict__ mean16, int N) {
    int b = blockIdx.x;
    int t = threadIdx.x;
    if (b < nchunk) {
        __shared__ int h[NBUCK_MAX];
        for (int i = t; i < nbuck; i += 512) h[i] = 0;
        __syncthreads();
        int base = b * CHUNK;
        for (int i = t; i < CHUNK; i += 512) {
            int e = base + i;
            if (e < E) atomicAdd(&h[dst[e] >> 8], 1);
        }
        __syncthreads();
        int* row = hist2d + (size_t)b * NBUCK_MAX;
        for (int i = t; i < nbuck; i += 512) row[i] = h[i];
    } else {
        int w = t >> 6, j = t & 63;
        int q = j >> 3, l = j & 7;
        int i = (b - nchunk) * 8 + w;
        if (i >= N) return;
        const float4* e4 = (const float4*)emb16;  // row = 8 float4 (64 halfs)
        int t0 = tok[i * 16 + q];
        int t1 = tok[i * 16 + q + 8];
        float4 v0 = e4[(size_t)t0 * 8 + l];
        float4 v1 = e4[(size_t)t1 * 8 + l];
        const __half2* p0 = (const __half2*)&v0;
        const __half2* p1 = (const __half2*)&v1;
        __half2 a0 = __hadd2(p0[0], p1[0]);
        __half2 a1 = __hadd2(p0[1], p1[1]);
        __half2 a2 = __hadd2(p0[2], p1[2]);
        __half2 a3 = __hadd2(p0[3], p1[3]);
#pragma unroll
        for (int mask = 8; mask <= 32; mask <<= 1) {
            a0 = __hadd2(a0, shfl_xor_h2(a0, mask));
            a1 = __hadd2(a1, shfl_xor_h2(a1, mask));
            a2 = __hadd2(a2, shfl_xor_h2(a2, mask));
            a3 = __hadd2(a3, shfl_xor_h2(a3, mask));
        }
        if (q == 0) {
            __half2 inv = __floats2half2_rn(1.0f / 16.0f, 1.0f / 16.0f);
            float4 packed;
            __half2* pp = (__half2*)&packed;
            pp[0] = __hmul2(a0, inv);
            pp[1] = __hmul2(a1, inv);
            pp[2] = __hmul2(a2, inv);
            pp[3] = __hmul2(a3, inv);
            ((float4*)mean16)[(size_t)i * 8 + l] = packed;
        }
    }
}

// per-bucket exclusive scan over chunks -> chunkbase[chunk][bucket], total[bucket]
__global__ void chunk_scan_kernel(const int* __restrict__ hist2d, int* __restrict__ chunkbase,
                                  int* __restrict__ total, int nchunk) {
    int b = blockIdx.x;
    int lane = threadIdx.x;  // 0..63
    int run = 0;
    for (int c0 = 0; c0 < nchunk; c0 += 64) {
        int c = c0 + lane;
        int v = (c < nchunk) ? hist2d[(size_t)c * NBUCK_MAX + b] : 0;
        int s = v;
#pragma unroll
        for (int off = 1; off < 64; off <<= 1) {
            int u = __shfl_up(s, off);
            if (lane >= off) s += u;
        }
        if (c < nchunk) chunkbase[(size_t)c * NBUCK_MAX + b] = s - v + run;
        run += __shfl(s, 63);
    }
    if (lane == 0) total[b] = run;
}

// one-pass scatter; each block re-derives bucket_base from total[] via LDS scan
// (block 0 publishes bucket_base for downstream kernels). packed val = src | (dst&255)<<17
__global__ void binscatter_kernel(const int* __restrict__ src, const int* __restrict__ dst,
                                  const int* __restrict__ total,
                                  const int* __restrict__ chunkbase,
                                  int* __restrict__ bucket_base,
                                  int* __restrict__ staged, int E, int nbuck) {
    __shared__ int s[512];
    __shared__ int h[NBUCK_MAX];
    int t = threadIdx.x;
    int v = (t < nbuck) ? total[t] : 0;
    s[t] = v;
    __syncthreads();
    for (int off = 1; off < 512; off <<= 1) {
        int add = (t >= off) ? s[t - off] : 0;
        __syncthreads();
        s[t] += add;
        __syncthreads();
    }
    const int* cb = chunkbase + (size_t)blockIdx.x * NBUCK_MAX;
    if (t < nbuck) h[t] = (s[t] - v) + cb[t];
    if (blockIdx.x == 0) {
        if (t < nbuck) bucket_base[t] = s[t] - v;
        if (t == 511) bucket_base[nbuck] = s[511];
    }
    __syncthreads();
    int base = blockIdx.x * CHUNK;
    for (int i = t; i < CHUNK; i += 512) {
        int e = base + i;
        if (e < E) {
            int d = dst[e], sv = src[e];
            int b = d >> 8;
            int r = atomicAdd(&h[b], 1);
            staged[r] = sv | ((d & 255) << 17);
        }
    }
}

// per bucket: per-node degree -> row_start + dis (coalesced writes)
__global__ void bucket_count_kernel(const int* __restrict__ staged,
                                    const int* __restrict__ bucket_base,
                                    int* __restrict__ row_start, float* __restrict__ dis,
                                    int N, int E) {
    __shared__ int cnt[256];
    __shared__ int sc[256];
    int b = blockIdx.x;
    int t = threadIdx.x;
    cnt[t] = 0;
    __syncthreads();
    int rb0 = bucket_base[b], rb1 = bucket_base[b + 1];
    for (int i = rb0 + t; i < rb1; i += 256) atomicAdd(&cnt[staged[i] >> 17], 1);
    __syncthreads();
    int v = cnt[t];
    sc[t] = v;
    __syncthreads();
    for (int off = 1; off < 256; off <<= 1) {
        int add = (t >= off) ? sc[t - off] : 0;
        __syncthreads();
        sc[t] += add;
        __syncthreads();
    }
    int node = b * 256 + t;
    if (node < N) {
        row_start[node] = rb0 + sc[t] - v;  // exclusive
        dis[node] = rsqrtf(1.0f + (float)v);  // +1 self loop
    }
    if (b == 0 && t == 0) row_start[N] = E;
}

// per bucket: final WEIGHTLESS CSR (4 B: src | fp16(dis[src])<<17) + rowsum.
// dis>0 always => fp16 sign bit 0 => 15 payload bits fit beside the 17-bit src.
__global__ void csr_write_kernel(const int* __restrict__ staged,
                                 const int* __restrict__ bucket_base,
                                 const int* __restrict__ row_start,
                                 const float* __restrict__ dis,
                                 int* __restrict__ csr, float* __restrict__ rowsum, int N) {
    __shared__ int cur[256];
    __shared__ float dl[256];
    __shared__ float wsum[256];
    int b = blockIdx.x;
    int t = threadIdx.x;
    int node = b * 256 + t;
    cur[t] = (node < N) ? row_start[node] : 0;
    dl[t] = (node < N) ? dis[node] : 0.f;
    wsum[t] = 0.f;
    __syncthreads();
    int rb0 = bucket_base[b], rb1 = bucket_base[b + 1];
    for (int i = rb0 + t; i < rb1; i += 256) {
        int v = staged[i];
        int s = v & 131071;
        int dloc = v >> 17;
        __half hds = __float2half_rn(dis[s]);
        float w = __half2float(hds) * dl[dloc];  // rowsum matches gather-side precision
        int pos = atomicAdd(&cur[dloc], 1);
        csr[pos] = s | ((int)(__half_as_ushort(hds) & 0x7FFF) << 17);
        atomicAdd(&wsum[dloc], w);
    }
    __syncthreads();
    if (node < N) rowsum[node] = wsum[t] + dl[t] * dl[t];
}

// ---------------- fused agg64 + MFMA dense chain (r8 config, weightless CSR) ----------------
// block = 32 nodes, 4 waves. Phase 1: 8 threads per node (nl=t>>3, l=t&7 feature float4),
// all 32 nodes' gather chains concurrent. Accumulates sum' = d*mean[node] + SUM dis_s*mean[s];
// final scale by d gives d^2*mean[node] + SUM (dis_s*d)*mean[s]. Phase 2: MFMA dense chain.
#define NB 32
__global__ __launch_bounds__(256, 6)
void agg64_dense_kernel(const __half* __restrict__ mean16,
                        const int* __restrict__ row_start,
                        const int* __restrict__ csr,
                        const float* __restrict__ dis,
                        const float* __restrict__ rowsum,
                        const _Float16* __restrict__ Wf16t,  // [128][64]
                        const float* __restrict__ bf,
                        const float* __restrict__ b1,
                        const _Float16* __restrict__ W2t,    // [128][128]
                        __half* __restrict__ h2, int N) {
    __shared__ _Float16 sagg[32][72];
    __shared__ _Float16 sx1[32][136];
    __shared__ float srs[32];
    int t = threadIdx.x;
    int nb0 = blockIdx.x * NB;
    const float4* m4 = (const float4*)mean16;  // row = 8 float4 (64 halfs)
    const unsigned* csru = (const unsigned*)csr;

    if (t < 32) srs[t] = (nb0 + t < N) ? rowsum[nb0 + t] : 0.f;

    // ---- phase 1: gather, 8 threads per node, 32 nodes in parallel ----
    {
        int nl = t >> 3;   // node_local 0..31
        int l = t & 7;     // feature float4 block 0..7
        int node = nb0 + nl;
        __half2 a0, a1, a2, a3;
        a0 = a1 = a2 = a3 = __floats2half2_rn(0.f, 0.f);
        float d = 0.f;
        if (node < N) {
            int beg = row_start[node];
            int end = row_start[node + 1];
            d = dis[node];
            {
                float4 raw = m4[(size_t)node * 8 + l];
                const __half2* hp = (const __half2*)&raw;
                __half2 dh = __floats2half2_rn(d, d);  // self term: d*mean (pre-final-scale)
                a0 = __hmul2(hp[0], dh); a1 = __hmul2(hp[1], dh);
                a2 = __hmul2(hp[2], dh); a3 = __hmul2(hp[3], dh);
            }
            int k = beg;
            int kfull = beg + ((end - beg) & ~7);
            for (; k < kfull; k += 8) {  // unguarded: 8 edges, all in flight
                unsigned e[8];
                float4 v[8];
#pragma unroll
                for (int m = 0; m < 8; m++) e[m] = csru[k + m];
#pragma unroll
                for (int m = 0; m < 8; m++) v[m] = m4[(size_t)(e[m] & 131071u) * 8 + l];
#pragma unroll
                for (int m = 0; m < 8; m++) {
                    unsigned s; __half2 wh;
                    unpack_csr(e[m], s, wh);
                    const __half2* hp = (const __half2*)&v[m];
                    a0 = __hfma2(hp[0], wh, a0);
                    a1 = __hfma2(hp[1], wh, a1);
                    a2 = __hfma2(hp[2], wh, a2);
                    a3 = __hfma2(hp[3], wh, a3);
                }
            }
            if (k < end) {  // single guarded round of 8
                unsigned e[8];
                float4 v[8];
#pragma unroll
                for (int m = 0; m < 8; m++) {
                    int kk = k + m;
                    e[m] = (kk < end) ? csru[kk] : 0u;  // wh=0 => no-op
                }
#pragma unroll
                for (int m = 0; m < 8; m++) v[m] = m4[(size_t)(e[m] & 131071u) * 8 + l];
#pragma unroll
                for (int m = 0; m < 8; m++) {
                    unsigned s; __half2 wh;
                    unpack_csr(e[m], s, wh);
                    const __half2* hp = (const __half2*)&v[m];
                    a0 = __hfma2(hp[0], wh, a0);
                    a1 = __hfma2(hp[1], wh, a1);
                    a2 = __hfma2(hp[2], wh, a2);
                    a3 = __hfma2(hp[3], wh, a3);
                }
            }
        }
        // deferred scale by dis[dst]
        __half2 dh2 = __floats2half2_rn(d, d);
        a0 = __hmul2(a0, dh2); a1 = __hmul2(a1, dh2);
        a2 = __hmul2(a2, dh2); a3 = __hmul2(a3, dh2);
        float4 packed;
        __half2* pp = (__half2*)&packed;
        pp[0] = a0; pp[1] = a1; pp[2] = a2; pp[3] = a3;
        *(float4*)(&sagg[nl][l * 8]) = packed;
    }
    __syncthreads();

    // ---- phase 2: MFMA dense chain ----
    int wv = t >> 6, lane = t & 63;
    int rh = wv & 1;
    int ncb = (wv >> 1) * 64;
    int m16 = lane & 15;
    int qq = lane >> 4;

    f32x4 c0 = {}, c1 = {}, c2 = {}, c3 = {};
#pragma unroll
    for (int ks = 0; ks < 2; ks++) {
        int k0 = ks * 32 + qq * 8;
        f16x8 afrag = *(const f16x8*)(&sagg[rh * 16 + m16][k0]);
        f16x8 b0 = *(const f16x8*)(Wf16t + (size_t)(ncb + 0 * 16 + m16) * 64 + k0);
        f16x8 b1f = *(const f16x8*)(Wf16t + (size_t)(ncb + 1 * 16 + m16) * 64 + k0);
        f16x8 b2f = *(const f16x8*)(Wf16t + (size_t)(ncb + 2 * 16 + m16) * 64 + k0);
        f16x8 b3f = *(const f16x8*)(Wf16t + (size_t)(ncb + 3 * 16 + m16) * 64 + k0);
        c0 = __builtin_amdgcn_mfma_f32_16x16x32_f16(afrag, b0, c0, 0, 0, 0);
        c1 = __builtin_amdgcn_mfma_f32_16x16x32_f16(afrag, b1f, c1, 0, 0, 0);
        c2 = __builtin_amdgcn_mfma_f32_16x16x32_f16(afrag, b2f, c2, 0, 0, 0);
        c3 = __builtin_amdgcn_mfma_f32_16x16x32_f16(afrag, b3f, c3, 0, 0, 0);
    }
    {
        f32x4 cc[4] = {c0, c1, c2, c3};
#pragma unroll
        for (int nt = 0; nt < 4; nt++) {
            int ncol = ncb + nt * 16 + m16;
            float bfj = bf[ncol], b1j = b1[ncol];
#pragma unroll
            for (int r = 0; r < 4; r++) {
                int mrow = qq * 4 + r;
                float z = cc[nt][r] + srs[rh * 16 + mrow] * bfj + b1j;
                sx1[rh * 16 + mrow][ncol] = (_Float16)fmaxf(z, 0.f);
            }
        }
    }
    __syncthreads();

    f32x4 d0 = {}, d1 = {}, d2 = {}, d3 = {};
#pragma unroll
    for (int ks = 0; ks < 4; ks++) {
        int k0 = ks * 32 + qq * 8;
        f16x8 afrag = *(const f16x8*)(&sx1[rh * 16 + m16][k0]);
        f16x8 b0 = *(const f16x8*)(W2t + (size_t)(ncb + 0 * 16 + m16) * 128 + k0);
        f16x8 b1f = *(const f16x8*)(W2t + (size_t)(ncb + 1 * 16 + m16) * 128 + k0);
        f16x8 b2f = *(const f16x8*)(W2t + (size_t)(ncb + 2 * 16 + m16) * 128 + k0);
        f16x8 b3f = *(const f16x8*)(W2t + (size_t)(ncb + 3 * 16 + m16) * 128 + k0);
        d0 = __builtin_amdgcn_mfma_f32_16x16x32_f16(afrag, b0, d0, 0, 0, 0);
        d1 = __builtin_amdgcn_mfma_f32_16x16x32_f16(afrag, b1f, d1, 0, 0, 0);
        d2 = __builtin_amdgcn_mfma_f32_16x16x32_f16(afrag, b2f, d2, 0, 0, 0);
        d3 = __builtin_amdgcn_mfma_f32_16x16x32_f16(afrag, b3f, d3, 0, 0, 0);
    }
    {
        f32x4 dd[4] = {d0, d1, d2, d3};
#pragma unroll
        for (int nt = 0; nt < 4; nt++) {
            int ncol = ncb + nt * 16 + m16;
#pragma unroll
            for (int r = 0; r < 4; r++) {
                int node = nb0 + rh * 16 + qq * 4 + r;
                if (node < N) h2[(size_t)node * 128 + ncol] = __float2half(dd[nt][r]);
            }
        }
    }
}

// ---------------- layer 2: agg128, 1 wave/node, weightless CSR, deferred dis[dst] in fp32 epilogue ----------------
// lane (q,l): q=j>>4 edge slot (4), l=j&15 feature block (float4 = 4 half2)
__global__ __launch_bounds__(256, 8)
void gcn_agg128_kernel(const __half* __restrict__ hsrc,
                       const int* __restrict__ row_start,
                       const int* __restrict__ csr,
                       const float* __restrict__ dis,
                       const float* __restrict__ b2,
                       __half* __restrict__ outx, int N) {
    int t = threadIdx.x;
    int w = t >> 6, j = t & 63;
    int q = j >> 4, l = j & 15;
    int node = blockIdx.x * 4 + w;
    if (node >= N) return;
    const float4* h4 = (const float4*)hsrc;  // row = 16 float4 (128 halfs)
    const unsigned* csru = (const unsigned*)csr;
    int beg = row_start[node];
    int end = row_start[node + 1];
    float d = dis[node];
    __half2 a0, a1, a2, a3;
    {
        float4 raw = h4[(size_t)node * 16 + l];
        const __half2* hp = (const __half2*)&raw;
        float df = d * ((q == 0) ? 1.f : 0.f);  // self term d*h (final *d in epilogue)
        __half2 dh = __floats2half2_rn(df, df);
        a0 = __hmul2(hp[0], dh); a1 = __hmul2(hp[1], dh);
        a2 = __hmul2(hp[2], dh); a3 = __hmul2(hp[3], dh);
    }
    int k = beg;
    int kfull = beg + ((end - beg) & ~31);
    for (; k < kfull; k += 32) {  // unguarded: 8 batches x 4 slots
        unsigned e[8];
        float4 v[8];
#pragma unroll
        for (int m = 0; m < 8; m++) e[m] = csru[k + 4 * m + q];
#pragma unroll
        for (int m = 0; m < 8; m++) v[m] = h4[(size_t)(e[m] & 131071u) * 16 + l];
#pragma unroll
        for (int m = 0; m < 8; m++) {
            unsigned s; __half2 wh;
            unpack_csr(e[m], s, wh);
            const __half2* hp = (const __half2*)&v[m];
            a0 = __hfma2(hp[0], wh, a0);
            a1 = __hfma2(hp[1], wh, a1);
            a2 = __hfma2(hp[2], wh, a2);
            a3 = __hfma2(hp[3], wh, a3);
        }
    }
    if (k < end) {  // single guarded round: 8 batches x 4 slots = 32 edges
        unsigned e[8];
        float4 v[8];
#pragma unroll
        for (int m = 0; m < 8; m++) {
            int kk = k + 4 * m + q;
            e[m] = (kk < end) ? csru[kk] : 0u;  // wh=0 => no-op
        }
#pragma unroll
        for (int m = 0; m < 8; m++) v[m] = h4[(size_t)(e[m] & 131071u) * 16 + l];
#pragma unroll
        for (int m = 0; m < 8; m++) {
            unsigned s; __half2 wh;
            unpack_csr(e[m], s, wh);
            const __half2* hp = (const __half2*)&v[m];
            a0 = __hfma2(hp[0], wh, a0);
            a1 = __hfma2(hp[1], wh, a1);
            a2 = __hfma2(hp[2], wh, a2);
            a3 = __hfma2(hp[3], wh, a3);
        }
    }
    // fold across q (lane bits 4,5)
#pragma unroll
    for (int mask = 16; mask <= 32; mask <<= 1) {
        a0 = __hadd2(a0, shfl_xor_h2(a0, mask));
        a1 = __hadd2(a1, shfl_xor_h2(a1, mask));
        a2 = __hadd2(a2, shfl_xor_h2(a2, mask));
        a3 = __hadd2(a3, shfl_xor_h2(a3, mask));
    }
    if (q == 0) {
        // fp32 epilogue: deferred *dis[dst] (fp32), + b2, relu, pack fp16
        float2 f0 = __half22float2(a0), f1 = __half22float2(a1);
        float2 f2 = __half22float2(a2), f3 = __half22float2(a3);
        const float4* b4 = (const float4*)b2;
        float4 ba = b4[l * 2], bb = b4[l * 2 + 1];
        __half2 o0 = __floats2half2_rn(fmaxf(f0.x * d + ba.x, 0.f), fmaxf(f0.y * d + ba.y, 0.f));
        __half2 o1 = __floats2half2_rn(fmaxf(f1.x * d + ba.z, 0.f), fmaxf(f1.y * d + ba.w, 0.f));
        __half2 o2 = __floats2half2_rn(fmaxf(f2.x * d + bb.x, 0.f), fmaxf(f2.y * d + bb.y, 0.f));
        __half2 o3 = __floats2half2_rn(fmaxf(f3.x * d + bb.z, 0.f), fmaxf(f3.y * d + bb.w, 0.f));
        float4 packed;
        __half2* pp = (__half2*)&packed;
        pp[0] = o0; pp[1] = o1; pp[2] = o2; pp[3] = o3;
        ((float4*)outx)[(size_t)node * 16 + l] = packed;
    }
}

// ---------------- fused pool + head: one block (256 threads, 4 row-waves) per graph ----------------
__device__ __forceinline__ int lower_bound_i(const int* __restrict__ a, int n, int val) {
    int lo = 0, hi = n;
    while (lo < hi) {
        int mid = (lo + hi) >> 1;
        if (a[mid] < val) lo = mid + 1; else hi = mid;
    }
    return lo;
}

__global__ void pool_head_kernel(const __half* __restrict__ x,
                                 const int* __restrict__ batch,
                                 const float* __restrict__ Wfc,
                                 const float* __restrict__ bfc,
                                 const float* __restrict__ Wout,
                                 const float* __restrict__ bout,
                                 float* __restrict__ out, int N) {
    int gr = blockIdx.x;
    int t = threadIdx.x;  // 0..255
    int j2 = t & 63, w = t >> 6;  // 4 row-waves
    __shared__ float2 spart[4][64];
    __shared__ float sg[128];
    __shared__ float sfc[2][128];
    __shared__ float sred[128];
    int beg = lower_bound_i(batch, N, gr);
    int end = lower_bound_i(batch, N, gr + 1);
    const __half2* x2 = (const __half2*)x;  // row stride 64 half2
    float2 acc = make_float2(0.f, 0.f);
    for (int i = beg + w; i < end; i += 4) {
        float2 a = __half22float2(x2[(size_t)i * 64 + j2]);
        acc.x += a.x; acc.y += a.y;
    }
    spart[w][j2] = acc;
    __syncthreads();
    if (t < 64) {
        float inv = 1.0f / fmaxf((float)(end - beg), 1.0f);
        float2 s0 = spart[0][t], s1 = spart[1][t];
        float2 s2 = spart[2][t], s3 = spart[3][t];
        sg[2 * t] = (s0.x + s1.x + s2.x + s3.x) * inv;
        sg[2 * t + 1] = (s0.y + s1.y + s2.y + s3.y) * inv;
    }
    __syncthreads();
    // FC: 256 threads, output j = t&127, k-half = t>>7
    int j = t & 127, hb = t >> 7;
    float a = 0.f;
#pragma unroll
    for (int k = 0; k < 64; k++) a += sg[hb * 64 + k] * Wfc[(hb * 64 + k) * 128 + j];
    sfc[hb][j] = a;
    __syncthreads();
    if (t < 128) {
        float aa = sfc[0][t] + sfc[1][t] + bfc[t];
        float f = fmaxf(aa, 0.f);
        sred[t] = f * Wout[t];
    }
    __syncthreads();
    if (t < 64) {
        float v = sred[t] + sred[t + 64];
#pragma unroll
        for (int off = 32; off > 0; off >>= 1) v += __shfl_down(v, off);
        if (t == 0) {
            float logit = v + bout[0];
            out[gr] = 1.0f / (1.0f + expf(-logit));
            out[NUM_GRAPHS + gr] = logit;
        }
    }
}

extern "C" void kernel_launch(void* const* d_in, const int* in_sizes, int n_in,
                              void* d_out, int out_size, void* d_ws, size_t ws_size,
                              hipStream_t stream) {
    const int* tok   = (const int*)d_in[0];
    const int* eidx  = (const int*)d_in[1];
    const int* batch = (const int*)d_in[2];
    const float* emb = (const float*)d_in[3];
    const float* Wp  = (const float*)d_in[4];
    const float* bp  = (const float*)d_in[5];
    const float* W1  = (const float*)d_in[6];
    const float* b1  = (const float*)d_in[7];
    const float* W2  = (const float*)d_in[8];
    const float* b2  = (const float*)d_in[9];
    const float* Wfc = (const float*)d_in[10];
    const float* bfc = (const float*)d_in[11];
    const float* Wout= (const float*)d_in[12];
    const float* bout= (const float*)d_in[13];
    float* out = (float*)d_out;

    const int N = in_sizes[2];
    const int E = in_sizes[1] / 2;
    const int* src = eidx;
    const int* dst = eidx + E;
    const int Np = (N + 3) & ~3;
    const int nbuck = (N + 255) / 256;               // 391 for N=100k
    const int nchunk = (E + CHUNK - 1) / CHUNK;      // 196
    const int emb_n4 = in_sizes[3] / 4;              // float4 count of emb

    // workspace layout (float units)
    float* ws = (float*)d_ws;
    size_t off = 0;
    float* dis     = ws + off;            off += Np;
    __half* mean16 = (__half*)(ws + off); off += (size_t)Np * 32;
    __half* agg16  = (__half*)(ws + off); off += (size_t)Np * 32;  // unused (layout stability)
    float* rowsum  = ws + off;            off += Np;
    __half* h2buf  = (__half*)(ws + off); off += (size_t)Np * 64;
    __half* xfin16 = (__half*)(ws + off); off += (size_t)Np * 64;
    __half* emb16  = (__half*)(ws + off); off += (size_t)(in_sizes[3] / 2 + 4);
    _Float16* Wf16t = (_Float16*)(ws + off); off += 4096;
    _Float16* W2t   = (_Float16*)(ws + off); off += 8192;
    float* bf      = ws + off;            off += 128;
    int* row_start = (int*)(ws + off);    off += Np + 4;
    int* staged    = (int*)(ws + off);    off += E;
    int* total     = (int*)(ws + off);    off += NBUCK_MAX;
    int* bucket_base   = (int*)(ws + off); off += NBUCK_MAX + 8;
    int* csr       = (int*)(ws + off);    // E ints (weightless CSR)
    // hist2d / chunkbase alias h2buf: only live during the sort pipeline, h2buf is
    // first written by agg64_dense_kernel which runs strictly after csr_write.
    int* hist2d    = (int*)h2buf;                        // [nchunk][NBUCK_MAX]
    int* chunkbase = hist2d + (size_t)nchunk * NBUCK_MAX;  // [nchunk][NBUCK_MAX]

    // --- fused weight prep + emb fp16 conversion (one launch) ---
    prep_fused_kernel<<<128 + (emb_n4 + 255) / 256, 256, 0, stream>>>(
        Wp, W1, W2, bp, emb, Wf16t, W2t, bf, emb16, emb_n4);

    // --- combined: bucket hist + embed/token-mean (one launch) ---
    hist_embed_kernel<<<nchunk + (N + 7) / 8, 512, 0, stream>>>(
        dst, hist2d, E, nbuck, nchunk, tok, emb16, mean16, N);

    // --- per-bucket chunk scan -> chunkbase, total ---
    chunk_scan_kernel<<<nbuck, 64, 0, stream>>>(hist2d, chunkbase, total, nchunk);

    // --- one-pass scatter (derives bucket_base in-LDS; block 0 publishes it) ---
    binscatter_kernel<<<nchunk, 512, 0, stream>>>(src, dst, total, chunkbase,
                                                  bucket_base, staged, E, nbuck);

    bucket_count_kernel<<<nbuck, 256, 0, stream>>>(staged, bucket_base, row_start, dis, N, E);
    csr_write_kernel<<<nbuck, 256, 0, stream>>>(staged, bucket_base, row_start, dis,
                                                csr, rowsum, N);

    // --- fused: 64-dim aggregate (8 thr/node, weightless CSR) + MFMA dense chain -> h2buf ---
    agg64_dense_kernel<<<(N + NB - 1) / NB, 256, 0, stream>>>(mean16, row_start, csr, dis,
                                                              rowsum, Wf16t, bf, b1, W2t,
                                                              h2buf, N);

    // --- layer 2 aggregate (weightless CSR, fp32 deferred dis[dst]) + b2 + ReLU -> xfin16 ---
    gcn_agg128_kernel<<<(N + 3) / 4, 256, 0, stream>>>(h2buf, row_start, csr, dis, b2,
                                                       xfin16, N);

    // --- fused global mean pool + head ---
    pool_head_kernel<<<NUM_GRAPHS, 256, 0, stream>>>(xfin16, batch, Wfc, bfc, Wout, bout,
                                                     out, N);
}

// Round 13
// 293.872 us; speedup vs baseline: 1.2242x; 1.0017x over previous
//
#include <hip/hip_runtime.h>
#include <hip/hip_bf16.h>
#include <hip/hip_fp16.h>
#include <math.h>

#define N_TOKENS 16
#define TOK_DIM 64
#define NODE_DIM 64
#define HID 128
#define FC 128
#define NUM_GRAPHS 1024
#define NBUCK_MAX 512
#define CHUNK 8192

typedef _Float16 f16x8 __attribute__((ext_vector_type(8)));
typedef float f32x4 __attribute__((ext_vector_type(4)));

__device__ __forceinline__ __half2 shfl_xor_h2(__half2 v, int mask) {
    int i = *(int*)&v;
    i = __shfl_xor(i, mask);
    return *(__half2*)&i;
}

// unpack weightless-CSR entry: low 17 bits = src, high 15 bits = fp16(dis[src]) sans sign
__device__ __forceinline__ void unpack_csr(unsigned e, unsigned& s, __half2& wh) {
    s = e & 131071u;
    __half hd = __ushort_as_half((unsigned short)(e >> 17));
    wh = __halves2half2(hd, hd);
}

// ---------------- fused prep: weights (blocks 0..127) + emb fp32->fp16 (rest) ----------------
__global__ void prep_fused_kernel(const float* __restrict__ Wp, const float* __restrict__ W1,
                                  const float* __restrict__ W2, const float* __restrict__ bp,
                                  const float* __restrict__ emb,
                                  _Float16* __restrict__ Wf16t, _Float16* __restrict__ W2t,
                                  float* __restrict__ bf, __half* __restrict__ emb16, int n4) {
    int b = blockIdx.x;
    int t = threadIdx.x;
    if (b < 128) {
        int n = b;
        if (t < 64) {
            float acc = 0.f;
#pragma unroll
            for (int d = 0; d < 64; d++) acc += Wp[t * 64 + d] * W1[d * 128 + n];
            Wf16t[(size_t)n * 64 + t] = (_Float16)acc;
        } else if (t < 128) {
            int d = t - 64;  // lane of wave 1
            float v = bp[d] * W1[d * 128 + n];
#pragma unroll
            for (int off = 32; off > 0; off >>= 1) v += __shfl_down(v, off);
            if (d == 0) bf[n] = v;
        }
        if (t < 128) W2t[(size_t)n * 128 + t] = (_Float16)W2[(size_t)t * 128 + n];
    } else {
        int i = (b - 128) * 256 + t;
        if (i < n4) {
            float4 v = ((const float4*)emb)[i];
            __half2 h0 = __floats2half2_rn(v.x, v.y);
            __half2 h1 = __floats2half2_rn(v.z, v.w);
            float2 p;
            ((__half2*)&p)[0] = h0;
            ((__half2*)&p)[1] = h1;
            ((float2*)emb16)[i] = p;
        }
    }
}

// ---------------- combined: bucket hist (blocks 0..nchunk-1) + embed/token-mean (rest) ----------------
__global__ void hist_embed_kernel(const int* __restrict__ dst, int* __restrict__ hist2d,
                                  int E, int nbuck, int nchunk,
                                  const int* __restrict__ tok,
                                  const __half* __restrict__ emb16,
                                  __half* __restrict__ mean16, int N) {
    int b = blockIdx.x;
    int t = threadIdx.x;
    if (b < nchunk) {
        __shared__ int h[NBUCK_MAX];
        for (int i = t; i < nbuck; i += 512) h[i] = 0;
        __syncthreads();
        int base = b * CHUNK;
        for (int i = t; i < CHUNK; i += 512) {
            int e = base + i;
            if (e < E) atomicAdd(&h[dst[e] >> 8], 1);
        }
        __syncthreads();
        int* row = hist2d + (size_t)b * NBUCK_MAX;
        for (int i = t; i < nbuck; i += 512) row[i] = h[i];
    } else {
        int w = t >> 6, j = t & 63;
        int q = j >> 3, l = j & 7;
        int i = (b - nchunk) * 8 + w;
        if (i >= N) return;
        const float4* e4 = (const float4*)emb16;  // row = 8 float4 (64 halfs)
        int t0 = tok[i * 16 + q];
        int t1 = tok[i * 16 + q + 8];
        float4 v0 = e4[(size_t)t0 * 8 + l];
        float4 v1 = e4[(size_t)t1 * 8 + l];
        const __half2* p0 = (const __half2*)&v0;
        const __half2* p1 = (const __half2*)&v1;
        __half2 a0 = __hadd2(p0[0], p1[0]);
        __half2 a1 = __hadd2(p0[1], p1[1]);
        __half2 a2 = __hadd2(p0[2], p1[2]);
        __half2 a3 = __hadd2(p0[3], p1[3]);
#pragma unroll
        for (int mask = 8; mask <= 32; mask <<= 1) {
            a0 = __hadd2(a0, shfl_xor_h2(a0, mask));
            a1 = __hadd2(a1, shfl_xor_h2(a1, mask));
            a2 = __hadd2(a2, shfl_xor_h2(a2, mask));
            a3 = __hadd2(a3, shfl_xor_h2(a3, mask));
        }
        if (q == 0) {
            __half2 inv = __floats2half2_rn(1.0f / 16.0f, 1.0f / 16.0f);
            float4 packed;
            __half2* pp = (__half2*)&packed;
            pp[0] = __hmul2(a0, inv);
            pp[1] = __hmul2(a1, inv);
            pp[2] = __hmul2(a2, inv);
            pp[3] = __hmul2(a3, inv);
            ((float4*)mean16)[(size_t)i * 8 + l] = packed;
        }
    }
}

// per-bucket exclusive scan over chunks -> chunkbase[chunk][bucket], total[bucket]
__global__ void chunk_scan_kernel(const int* __restrict__ hist2d, int* __restrict__ chunkbase,
                                  int* __restrict__ total, int nchunk) {
    int b = blockIdx.x;
    int lane = threadIdx.x;  // 0..63
    int run = 0;
    for (int c0 = 0; c0 < nchunk; c0 += 64) {
        int c = c0 + lane;
        int v = (c < nchunk) ? hist2d[(size_t)c * NBUCK_MAX + b] : 0;
        int s = v;
#pragma unroll
        for (int off = 1; off < 64; off <<= 1) {
            int u = __shfl_up(s, off);
            if (lane >= off) s += u;
        }
        if (c < nchunk) chunkbase[(size_t)c * NBUCK_MAX + b] = s - v + run;
        run += __shfl(s, 63);
    }
    if (lane == 0) total[b] = run;
}

// one-pass scatter; each block re-derives bucket_base from total[] via LDS scan
// (block 0 publishes bucket_base for downstream kernels). packed val = src | (dst&255)<<17
__global__ void binscatter_kernel(const int* __restrict__ src, const int* __restrict__ dst,
                                  const int* __restrict__ total,
                                  const int* __restrict__ chunkbase,
                                  int* __restrict__ bucket_base,
                                  int* __restrict__ staged, int E, int nbuck) {
    __shared__ int s[512];
    __shared__ int h[NBUCK_MAX];
    int t = threadIdx.x;
    int v = (t < nbuck) ? total[t] : 0;
    s[t] = v;
    __syncthreads();
    for (int off = 1; off < 512; off <<= 1) {
        int add = (t >= off) ? s[t - off] : 0;
        __syncthreads();
        s[t] += add;
        __syncthreads();
    }
    const int* cb = chunkbase + (size_t)blockIdx.x * NBUCK_MAX;
    if (t < nbuck) h[t] = (s[t] - v) + cb[t];
    if (blockIdx.x == 0) {
        if (t < nbuck) bucket_base[t] = s[t] - v;
        if (t == 511) bucket_base[nbuck] = s[511];
    }
    __syncthreads();
    int base = blockIdx.x * CHUNK;
    for (int i = t; i < CHUNK; i += 512) {
        int e = base + i;
        if (e < E) {
            int d = dst[e], sv = src[e];
            int b = d >> 8;
            int r = atomicAdd(&h[b], 1);
            staged[r] = sv | ((d & 255) << 17);
        }
    }
}

// per bucket: per-node degree -> row_start + dis (coalesced writes)
__global__ void bucket_count_kernel(const int* __restrict__ staged,
                                    const int* __restrict__ bucket_base,
                                    int* __restrict__ row_start, float* __restrict__ dis,
                                    int N, int E) {
    __shared__ int cnt[256];
    __shared__ int sc[256];
    int b = blockIdx.x;
    int t = threadIdx.x;
    cnt[t] = 0;
    __syncthreads();
    int rb0 = bucket_base[b], rb1 = bucket_base[b + 1];
    for (int i = rb0 + t; i < rb1; i += 256) atomicAdd(&cnt[staged[i] >> 17], 1);
    __syncthreads();
    int v = cnt[t];
    sc[t] = v;
    __syncthreads();
    for (int off = 1; off < 256; off <<= 1) {
        int add = (t >= off) ? sc[t - off] : 0;
        __syncthreads();
        sc[t] += add;
        __syncthreads();
    }
    int node = b * 256 + t;
    if (node < N) {
        row_start[node] = rb0 + sc[t] - v;  // exclusive
        dis[node] = rsqrtf(1.0f + (float)v);  // +1 self loop
    }
    if (b == 0 && t == 0) row_start[N] = E;
}

// per bucket: final WEIGHTLESS CSR (4 B: src | fp16(dis[src])<<17) + rowsum.
// dis>0 always => fp16 sign bit 0 => 15 payload bits fit beside the 17-bit src.
__global__ void csr_write_kernel(const int* __restrict__ staged,
                                 const int* __restrict__ bucket_base,
                                 const int* __restrict__ row_start,
                                 const float* __restrict__ dis,
                                 int* __restrict__ csr, float* __restrict__ rowsum, int N) {
    __shared__ int cur[256];
    __shared__ float dl[256];
    __shared__ float wsum[256];
    int b = blockIdx.x;
    int t = threadIdx.x;
    int node = b * 256 + t;
    cur[t] = (node < N) ? row_start[node] : 0;
    dl[t] = (node < N) ? dis[node] : 0.f;
    wsum[t] = 0.f;
    __syncthreads();
    int rb0 = bucket_base[b], rb1 = bucket_base[b + 1];
    for (int i = rb0 + t; i < rb1; i += 256) {
        int v = staged[i];
        int s = v & 131071;
        int dloc = v >> 17;
        __half hds = __float2half_rn(dis[s]);
        float w = __half2float(hds) * dl[dloc];  // rowsum matches gather-side precision
        int pos = atomicAdd(&cur[dloc], 1);
        csr[pos] = s | ((int)(__half_as_ushort(hds) & 0x7FFF) << 17);
        atomicAdd(&wsum[dloc], w);
    }
    __syncthreads();
    if (node < N) rowsum[node] = wsum[t] + dl[t] * dl[t];
}

// ---------------- fused agg64 + MFMA dense chain (weightless CSR, launch_bounds 6->8) ----------------
// block = 32 nodes, 4 waves. Phase 1: 8 threads per node (nl=t>>3, l=t&7 feature float4),
// all 32 nodes' gather chains concurrent. launch_bounds(256,8): LDS 13.8 KB x 8 = 110 KB
// fits 160 KB; VGPR 32 x 32 waves fits the RF -> raises TLP 24->32 waves/CU for the
// latency-bound gather (r12 occupancy was 62% at the inherited bound of 6).
// Phase 2: MFMA dense chain.
#define NB 32
__global__ __launch_bounds__(256, 8)
void agg64_dense_kernel(const __half* __restrict__ mean16,
                        const int* __restrict__ row_start,
                        const int* __restrict__ csr,
                        const float* __restrict__ dis,
                        const float* __restrict__ rowsum,
                        const _Float16* __restrict__ Wf16t,  // [128][64]
                        const float* __restrict__ bf,
                        const float* __restrict__ b1,
                        const _Float16* __restrict__ W2t,    // [128][128]
                        __half* __restrict__ h2, int N) {
    __shared__ _Float16 sagg[32][72];
    __shared__ _Float16 sx1[32][136];
    __shared__ float srs[32];
    int t = threadIdx.x;
    int nb0 = blockIdx.x * NB;
    const float4* m4 = (const float4*)mean16;  // row = 8 float4 (64 halfs)
    const unsigned* csru = (const unsigned*)csr;

    if (t < 32) srs[t] = (nb0 + t < N) ? rowsum[nb0 + t] : 0.f;

    // ---- phase 1: gather, 8 threads per node, 32 nodes in parallel ----
    {
        int nl = t >> 3;   // node_local 0..31
        int l = t & 7;     // feature float4 block 0..7
        int node = nb0 + nl;
        __half2 a0, a1, a2, a3;
        a0 = a1 = a2 = a3 = __floats2half2_rn(0.f, 0.f);
        float d = 0.f;
        if (node < N) {
            int beg = row_start[node];
            int end = row_start[node + 1];
            d = dis[node];
            {
                float4 raw = m4[(size_t)node * 8 + l];
                const __half2* hp = (const __half2*)&raw;
                __half2 dh = __floats2half2_rn(d, d);  // self term: d*mean (pre-final-scale)
                a0 = __hmul2(hp[0], dh); a1 = __hmul2(hp[1], dh);
                a2 = __hmul2(hp[2], dh); a3 = __hmul2(hp[3], dh);
            }
            int k = beg;
            int kfull = beg + ((end - beg) & ~7);
            for (; k < kfull; k += 8) {  // unguarded: 8 edges, all in flight
                unsigned e[8];
                float4 v[8];
#pragma unroll
                for (int m = 0; m < 8; m++) e[m] = csru[k + m];
#pragma unroll
                for (int m = 0; m < 8; m++) v[m] = m4[(size_t)(e[m] & 131071u) * 8 + l];
#pragma unroll
                for (int m = 0; m < 8; m++) {
                    unsigned s; __half2 wh;
                    unpack_csr(e[m], s, wh);
                    const __half2* hp = (const __half2*)&v[m];
                    a0 = __hfma2(hp[0], wh, a0);
                    a1 = __hfma2(hp[1], wh, a1);
                    a2 = __hfma2(hp[2], wh, a2);
                    a3 = __hfma2(hp[3], wh, a3);
                }
            }
            if (k < end) {  // single guarded round of 8
                unsigned e[8];
                float4 v[8];
#pragma unroll
                for (int m = 0; m < 8; m++) {
                    int kk = k + m;
                    e[m] = (kk < end) ? csru[kk] : 0u;  // wh=0 => no-op
                }
#pragma unroll
                for (int m = 0; m < 8; m++) v[m] = m4[(size_t)(e[m] & 131071u) * 8 + l];
#pragma unroll
                for (int m = 0; m < 8; m++) {
                    unsigned s; __half2 wh;
                    unpack_csr(e[m], s, wh);
                    const __half2* hp = (const __half2*)&v[m];
                    a0 = __hfma2(hp[0], wh, a0);
                    a1 = __hfma2(hp[1], wh, a1);
                    a2 = __hfma2(hp[2], wh, a2);
                    a3 = __hfma2(hp[3], wh, a3);
                }
            }
        }
        // deferred scale by dis[dst]
        __half2 dh2 = __floats2half2_rn(d, d);
        a0 = __hmul2(a0, dh2); a1 = __hmul2(a1, dh2);
        a2 = __hmul2(a2, dh2); a3 = __hmul2(a3, dh2);
        float4 packed;
        __half2* pp = (__half2*)&packed;
        pp[0] = a0; pp[1] = a1; pp[2] = a2; pp[3] = a3;
        *(float4*)(&sagg[nl][l * 8]) = packed;
    }
    __syncthreads();

    // ---- phase 2: MFMA dense chain ----
    int wv = t >> 6, lane = t & 63;
    int rh = wv & 1;
    int ncb = (wv >> 1) * 64;
    int m16 = lane & 15;
    int qq = lane >> 4;

    f32x4 c0 = {}, c1 = {}, c2 = {}, c3 = {};
#pragma unroll
    for (int ks = 0; ks < 2; ks++) {
        int k0 = ks * 32 + qq * 8;
        f16x8 afrag = *(const f16x8*)(&sagg[rh * 16 + m16][k0]);
        f16x8 b0 = *(const f16x8*)(Wf16t + (size_t)(ncb + 0 * 16 + m16) * 64 + k0);
        f16x8 b1f = *(const f16x8*)(Wf16t + (size_t)(ncb + 1 * 16 + m16) * 64 + k0);
        f16x8 b2f = *(const f16x8*)(Wf16t + (size_t)(ncb + 2 * 16 + m16) * 64 + k0);
        f16x8 b3f = *(const f16x8*)(Wf16t + (size_t)(ncb + 3 * 16 + m16) * 64 + k0);
        c0 = __builtin_amdgcn_mfma_f32_16x16x32_f16(afrag, b0, c0, 0, 0, 0);
        c1 = __builtin_amdgcn_mfma_f32_16x16x32_f16(afrag, b1f, c1, 0, 0, 0);
        c2 = __builtin_amdgcn_mfma_f32_16x16x32_f16(afrag, b2f, c2, 0, 0, 0);
        c3 = __builtin_amdgcn_mfma_f32_16x16x32_f16(afrag, b3f, c3, 0, 0, 0);
    }
    {
        f32x4 cc[4] = {c0, c1, c2, c3};
#pragma unroll
        for (int nt = 0; nt < 4; nt++) {
            int ncol = ncb + nt * 16 + m16;
            float bfj = bf[ncol], b1j = b1[ncol];
#pragma unroll
            for (int r = 0; r < 4; r++) {
                int mrow = qq * 4 + r;
                float z = cc[nt][r] + srs[rh * 16 + mrow] * bfj + b1j;
                sx1[rh * 16 + mrow][ncol] = (_Float16)fmaxf(z, 0.f);
            }
        }
    }
    __syncthreads();

    f32x4 d0 = {}, d1 = {}, d2 = {}, d3 = {};
#pragma unroll
    for (int ks = 0; ks < 4; ks++) {
        int k0 = ks * 32 + qq * 8;
        f16x8 afrag = *(const f16x8*)(&sx1[rh * 16 + m16][k0]);
        f16x8 b0 = *(const f16x8*)(W2t + (size_t)(ncb + 0 * 16 + m16) * 128 + k0);
        f16x8 b1f = *(const f16x8*)(W2t + (size_t)(ncb + 1 * 16 + m16) * 128 + k0);
        f16x8 b2f = *(const f16x8*)(W2t + (size_t)(ncb + 2 * 16 + m16) * 128 + k0);
        f16x8 b3f = *(const f16x8*)(W2t + (size_t)(ncb + 3 * 16 + m16) * 128 + k0);
        d0 = __builtin_amdgcn_mfma_f32_16x16x32_f16(afrag, b0, d0, 0, 0, 0);
        d1 = __builtin_amdgcn_mfma_f32_16x16x32_f16(afrag, b1f, d1, 0, 0, 0);
        d2 = __builtin_amdgcn_mfma_f32_16x16x32_f16(afrag, b2f, d2, 0, 0, 0);
        d3 = __builtin_amdgcn_mfma_f32_16x16x32_f16(afrag, b3f, d3, 0, 0, 0);
    }
    {
        f32x4 dd[4] = {d0, d1, d2, d3};
#pragma unroll
        for (int nt = 0; nt < 4; nt++) {
            int ncol = ncb + nt * 16 + m16;
#pragma unroll
            for (int r = 0; r < 4; r++) {
                int node = nb0 + rh * 16 + qq * 4 + r;
                if (node < N) h2[(size_t)node * 128 + ncol] = __float2half(dd[nt][r]);
            }
        }
    }
}

// ---------------- layer 2: agg128, 1 wave/node, weightless CSR, deferred dis[dst] in fp32 epilogue ----------------
// lane (q,l): q=j>>4 edge slot (4), l=j&15 feature block (float4 = 4 half2)
__global__ __launch_bounds__(256, 8)
void gcn_agg128_kernel(const __half* __restrict__ hsrc,
                       const int* __restrict__ row_start,
                       const int* __restrict__ csr,
                       const float* __restrict__ dis,
                       const float* __restrict__ b2,
                       __half* __restrict__ outx, int N) {
    int t = threadIdx.x;
    int w = t >> 6, j = t & 63;
    int q = j >> 4, l = j & 15;
    int node = blockIdx.x * 4 + w;
    if (node >= N) return;
    const float4* h4 = (const float4*)hsrc;  // row = 16 float4 (128 halfs)
    const unsigned* csru = (const unsigned*)csr;
    int beg = row_start[node];
    int end = row_start[node + 1];
    float d = dis[node];
    __half2 a0, a1, a2, a3;
    {
        float4 raw = h4[(size_t)node * 16 + l];
        const __half2* hp = (const __half2*)&raw;
        float df = d * ((q == 0) ? 1.f : 0.f);  // self term d*h (final *d in epilogue)
        __half2 dh = __floats2half2_rn(df, df);
        a0 = __hmul2(hp[0], dh); a1 = __hmul2(hp[1], dh);
        a2 = __hmul2(hp[2], dh); a3 = __hmul2(hp[3], dh);
    }
    int k = beg;
    int kfull = beg + ((end - beg) & ~31);
    for (; k < kfull; k += 32) {  // unguarded: 8 batches x 4 slots
        unsigned e[8];
        float4 v[8];
#pragma unroll
        for (int m = 0; m < 8; m++) e[m] = csru[k + 4 * m + q];
#pragma unroll
        for (int m = 0; m < 8; m++) v[m] = h4[(size_t)(e[m] & 131071u) * 16 + l];
#pragma unroll
        for (int m = 0; m < 8; m++) {
            unsigned s; __half2 wh;
            unpack_csr(e[m], s, wh);
            const __half2* hp = (const __half2*)&v[m];
            a0 = __hfma2(hp[0], wh, a0);
            a1 = __hfma2(hp[1], wh, a1);
            a2 = __hfma2(hp[2], wh, a2);
            a3 = __hfma2(hp[3], wh, a3);
        }
    }
    if (k < end) {  // single guarded round: 8 batches x 4 slots = 32 edges
        unsigned e[8];
        float4 v[8];
#pragma unroll
        for (int m = 0; m < 8; m++) {
            int kk = k + 4 * m + q;
            e[m] = (kk < end) ? csru[kk] : 0u;  // wh=0 => no-op
        }
#pragma unroll
        for (int m = 0; m < 8; m++) v[m] = h4[(size_t)(e[m] & 131071u) * 16 + l];
#pragma unroll
        for (int m = 0; m < 8; m++) {
            unsigned s; __half2 wh;
            unpack_csr(e[m], s, wh);
            const __half2* hp = (const __half2*)&v[m];
            a0 = __hfma2(hp[0], wh, a0);
            a1 = __hfma2(hp[1], wh, a1);
            a2 = __hfma2(hp[2], wh, a2);
            a3 = __hfma2(hp[3], wh, a3);
        }
    }
    // fold across q (lane bits 4,5)
#pragma unroll
    for (int mask = 16; mask <= 32; mask <<= 1) {
        a0 = __hadd2(a0, shfl_xor_h2(a0, mask));
        a1 = __hadd2(a1, shfl_xor_h2(a1, mask));
        a2 = __hadd2(a2, shfl_xor_h2(a2, mask));
        a3 = __hadd2(a3, shfl_xor_h2(a3, mask));
    }
    if (q == 0) {
        // fp32 epilogue: deferred *dis[dst] (fp32), + b2, relu, pack fp16
        float2 f0 = __half22float2(a0), f1 = __half22float2(a1);
        float2 f2 = __half22float2(a2), f3 = __half22float2(a3);
        const float4* b4 = (const float4*)b2;
        float4 ba = b4[l * 2], bb = b4[l * 2 + 1];
        __half2 o0 = __floats2half2_rn(fmaxf(f0.x * d + ba.x, 0.f), fmaxf(f0.y * d + ba.y, 0.f));
        __half2 o1 = __floats2half2_rn(fmaxf(f1.x * d + ba.z, 0.f), fmaxf(f1.y * d + ba.w, 0.f));
        __half2 o2 = __floats2half2_rn(fmaxf(f2.x * d + bb.x, 0.f), fmaxf(f2.y * d + bb.y, 0.f));
        __half2 o3 = __floats2half2_rn(fmaxf(f3.x * d + bb.z, 0.f), fmaxf(f3.y * d + bb.w, 0.f));
        float4 packed;
        __half2* pp = (__half2*)&packed;
        pp[0] = o0; pp[1] = o1; pp[2] = o2; pp[3] = o3;
        ((float4*)outx)[(size_t)node * 16 + l] = packed;
    }
}

// ---------------- fused pool + head: one block (256 threads, 4 row-waves) per graph ----------------
__device__ __forceinline__ int lower_bound_i(const int* __restrict__ a, int n, int val) {
    int lo = 0, hi = n;
    while (lo < hi) {
        int mid = (lo + hi) >> 1;
        if (a[mid] < val) lo = mid + 1; else hi = mid;
    }
    return lo;
}

__global__ void pool_head_kernel(const __half* __restrict__ x,
                                 const int* __restrict__ batch,
                                 const float* __restrict__ Wfc,
                                 const float* __restrict__ bfc,
                                 const float* __restrict__ Wout,
                                 const float* __restrict__ bout,
                                 float* __restrict__ out, int N) {
    int gr = blockIdx.x;
    int t = threadIdx.x;  // 0..255
    int j2 = t & 63, w = t >> 6;  // 4 row-waves
    __shared__ float2 spart[4][64];
    __shared__ float sg[128];
    __shared__ float sfc[2][128];
    __shared__ float sred[128];
    int beg = lower_bound_i(batch, N, gr);
    int end = lower_bound_i(batch, N, gr + 1);
    const __half2* x2 = (const __half2*)x;  // row stride 64 half2
    float2 acc = make_float2(0.f, 0.f);
    for (int i = beg + w; i < end; i += 4) {
        float2 a = __half22float2(x2[(size_t)i * 64 + j2]);
        acc.x += a.x; acc.y += a.y;
    }
    spart[w][j2] = acc;
    __syncthreads();
    if (t < 64) {
        float inv = 1.0f / fmaxf((float)(end - beg), 1.0f);
        float2 s0 = spart[0][t], s1 = spart[1][t];
        float2 s2 = spart[2][t], s3 = spart[3][t];
        sg[2 * t] = (s0.x + s1.x + s2.x + s3.x) * inv;
        sg[2 * t + 1] = (s0.y + s1.y + s2.y + s3.y) * inv;
    }
    __syncthreads();
    // FC: 256 threads, output j = t&127, k-half = t>>7
    int j = t & 127, hb = t >> 7;
    float a = 0.f;
#pragma unroll
    for (int k = 0; k < 64; k++) a += sg[hb * 64 + k] * Wfc[(hb * 64 + k) * 128 + j];
    sfc[hb][j] = a;
    __syncthreads();
    if (t < 128) {
        float aa = sfc[0][t] + sfc[1][t] + bfc[t];
        float f = fmaxf(aa, 0.f);
        sred[t] = f * Wout[t];
    }
    __syncthreads();
    if (t < 64) {
        float v = sred[t] + sred[t + 64];
#pragma unroll
        for (int off = 32; off > 0; off >>= 1) v += __shfl_down(v, off);
        if (t == 0) {
            float logit = v + bout[0];
            out[gr] = 1.0f / (1.0f + expf(-logit));
            out[NUM_GRAPHS + gr] = logit;
        }
    }
}

extern "C" void kernel_launch(void* const* d_in, const int* in_sizes, int n_in,
                              void* d_out, int out_size, void* d_ws, size_t ws_size,
                              hipStream_t stream) {
    const int* tok   = (const int*)d_in[0];
    const int* eidx  = (const int*)d_in[1];
    const int* batch = (const int*)d_in[2];
    const float* emb = (const float*)d_in[3];
    const float* Wp  = (const float*)d_in[4];
    const float* bp  = (const float*)d_in[5];
    const float* W1  = (const float*)d_in[6];
    const float* b1  = (const float*)d_in[7];
    const float* W2  = (const float*)d_in[8];
    const float* b2  = (const float*)d_in[9];
    const float* Wfc = (const float*)d_in[10];
    const float* bfc = (const float*)d_in[11];
    const float* Wout= (const float*)d_in[12];
    const float* bout= (const float*)d_in[13];
    float* out = (float*)d_out;

    const int N = in_sizes[2];
    const int E = in_sizes[1] / 2;
    const int* src = eidx;
    const int* dst = eidx + E;
    const int Np = (N + 3) & ~3;
    const int nbuck = (N + 255) / 256;               // 391 for N=100k
    const int nchunk = (E + CHUNK - 1) / CHUNK;      // 196
    const int emb_n4 = in_sizes[3] / 4;              // float4 count of emb

    // workspace layout (float units)
    float* ws = (float*)d_ws;
    size_t off = 0;
    float* dis     = ws + off;            off += Np;
    __half* mean16 = (__half*)(ws + off); off += (size_t)Np * 32;
    __half* agg16  = (__half*)(ws + off); off += (size_t)Np * 32;  // unused (layout stability)
    float* rowsum  = ws + off;            off += Np;
    __half* h2buf  = (__half*)(ws + off); off += (size_t)Np * 64;
    __half* xfin16 = (__half*)(ws + off); off += (size_t)Np * 64;
    __half* emb16  = (__half*)(ws + off); off += (size_t)(in_sizes[3] / 2 + 4);
    _Float16* Wf16t = (_Float16*)(ws + off); off += 4096;
    _Float16* W2t   = (_Float16*)(ws + off); off += 8192;
    float* bf      = ws + off;            off += 128;
    int* row_start = (int*)(ws + off);    off += Np + 4;
    int* staged    = (int*)(ws + off);    off += E;
    int* total     = (int*)(ws + off);    off += NBUCK_MAX;
    int* bucket_base   = (int*)(ws + off); off += NBUCK_MAX + 8;
    int* csr       = (int*)(ws + off);    // E ints (weightless CSR)
    // hist2d / chunkbase alias h2buf: only live during the sort pipeline, h2buf is
    // first written by agg64_dense_kernel which runs strictly after csr_write.
    int* hist2d    = (int*)h2buf;                        // [nchunk][NBUCK_MAX]
    int* chunkbase = hist2d + (size_t)nchunk * NBUCK_MAX;  // [nchunk][NBUCK_MAX]

    // --- fused weight prep + emb fp16 conversion (one launch) ---
    prep_fused_kernel<<<128 + (emb_n4 + 255) / 256, 256, 0, stream>>>(
        Wp, W1, W2, bp, emb, Wf16t, W2t, bf, emb16, emb_n4);

    // --- combined: bucket hist + embed/token-mean (one launch) ---
    hist_embed_kernel<<<nchunk + (N + 7) / 8, 512, 0, stream>>>(
        dst, hist2d, E, nbuck, nchunk, tok, emb16, mean16, N);

    // --- per-bucket chunk scan -> chunkbase, total ---
    chunk_scan_kernel<<<nbuck, 64, 0, stream>>>(hist2d, chunkbase, total, nchunk);

    // --- one-pass scatter (derives bucket_base in-LDS; block 0 publishes it) ---
    binscatter_kernel<<<nchunk, 512, 0, stream>>>(src, dst, total, chunkbase,
                                                  bucket_base, staged, E, nbuck);

    bucket_count_kernel<<<nbuck, 256, 0, stream>>>(staged, bucket_base, row_start, dis, N, E);
    csr_write_kernel<<<nbuck, 256, 0, stream>>>(staged, bucket_base, row_start, dis,
                                                csr, rowsum, N);

    // --- fused: 64-dim aggregate (8 thr/node, weightless CSR, 8 blocks/CU) + MFMA dense chain ---
    agg64_dense_kernel<<<(N + NB - 1) / NB, 256, 0, stream>>>(mean16, row_start, csr, dis,
                                                              rowsum, Wf16t, bf, b1, W2t,
                                                              h2buf, N);

    // --- layer 2 aggregate (weightless CSR, fp32 deferred dis[dst]) + b2 + ReLU -> xfin16 ---
    gcn_agg128_kernel<<<(N + 3) / 4, 256, 0, stream>>>(h2buf, row_start, csr, dis, b2,
                                                       xfin16, N);

    // --- fused global mean pool + head ---
    pool_head_kernel<<<NUM_GRAPHS, 256, 0, stream>>>(xfin16, batch, Wfc, bfc, Wout, bout,
                                                     out, N);
}